// Round 1
// baseline (921.821 us; speedup 1.0000x reference)
//
#include <hip/hip_runtime.h>
#include <hip/hip_bf16.h>

#define NN 20000
#define NE 200000

typedef __bf16 bf16x8 __attribute__((ext_vector_type(8)));
typedef float f32x4 __attribute__((ext_vector_type(4)));

// ---- workspace layout (bytes) ----
// float tables at offset 0 (element offsets below), then bf16 weight copies, P, agg, deg
constexpr int TAB_MSG_SCALE = 0;      // 256 f32
constexpr int TAB_MSG_BETA  = 256;    // 256
constexpr int TAB_UPD_SCALE = 512;    // 256
constexpr int TAB_UPD_BETA  = 768;    // 256
constexpr int TAB_TASKC     = 1024;   // 256   task @ att_W1[768:1024] + att_b1
constexpr int TAB_EM        = 1280;   // 16*256  e@msg_W + msg_b
constexpr int TAB_EC        = 1280 + 4096; // 16*256  e@att_W1[512:768]
constexpr size_t OFF_WPRET = 40960;     // u16[768*256]  (n-major: row n, 256 k)
constexpr size_t OFF_W1T   = 434176;    // u16[256*512]  up_W1 transposed
constexpr size_t OFF_W2T   = 696320;    // u16[256*256]  up_W2 transposed
constexpr size_t OFF_P     = 1048576;   // u16[20000*768]  [M | P1 | P2] bf16
constexpr size_t OFF_AGG   = 31768576;  // f32[20000*256]
constexpr size_t OFF_DEG   = 52248576;  // f32[20000]
constexpr size_t WS_NEED   = 52328576;

__device__ __forceinline__ float bf2f(unsigned short u){
  union { unsigned int i; float f; } v; v.i = ((unsigned int)u) << 16; return v.f;
}
__device__ __forceinline__ unsigned short f2bf(float f){
  __bf16 h = (__bf16)f; unsigned short u; __builtin_memcpy(&u, &h, 2); return u;
}
__device__ __forceinline__ float gelu_f(float x){
  return 0.5f * x * (1.0f + erff(x * 0.70710678118654752f));
}

// ---------------- K0: tiny tables ----------------
__global__ __launch_bounds__(256) void k_tables(
    const float* __restrict__ task, const float* __restrict__ eemb,
    const float* __restrict__ msg_W, const float* __restrict__ msg_b,
    const float* __restrict__ att_W1, const float* __restrict__ att_b1,
    const float* __restrict__ ma_W1, const float* __restrict__ ma_b1,
    const float* __restrict__ ma_W2, const float* __restrict__ ma_b2,
    const float* __restrict__ ua_W1, const float* __restrict__ ua_b1,
    const float* __restrict__ ua_W2, const float* __restrict__ ua_b2,
    float* __restrict__ tabs)
{
  __shared__ float s_in[512];
  __shared__ float s_h[512];
  int b = blockIdx.x, tid = threadIdx.x;
  if (b < 2){
    const float* W1 = b ? ua_W1 : ma_W1;  const float* b1 = b ? ua_b1 : ma_b1;
    const float* W2 = b ? ua_W2 : ma_W2;  const float* b2 = b ? ua_b2 : ma_b2;
    s_in[tid] = task[tid];
    __syncthreads();
    #pragma unroll
    for (int jj = 0; jj < 2; ++jj){
      int j = tid + jj*256;
      float acc = b1[j];
      for (int k = 0; k < 256; ++k) acc += s_in[k] * W1[k*512 + j];
      s_h[j] = gelu_f(acc);
    }
    __syncthreads();
    float o[2];
    #pragma unroll
    for (int jj = 0; jj < 2; ++jj){
      int j = tid + jj*256;
      float acc = b2[j];
      for (int k = 0; k < 512; ++k) acc += s_h[k] * W2[k*512 + j];
      o[jj] = acc;
    }
    float* scale = tabs + (b ? TAB_UPD_SCALE : TAB_MSG_SCALE);
    float* beta  = tabs + (b ? TAB_UPD_BETA  : TAB_MSG_BETA);
    scale[tid] = 1.0f + 0.5f * tanhf(o[0]);
    beta[tid]  = o[1];
  } else if (b == 2){
    s_in[tid] = task[tid];
    __syncthreads();
    float acc = att_b1[tid];
    for (int k = 0; k < 256; ++k) acc += s_in[k] * att_W1[(768 + k)*256 + tid];
    tabs[TAB_TASKC + tid] = acc;
  } else if (b < 19){
    int t = b - 3;
    s_in[tid] = eemb[t*256 + tid];
    __syncthreads();
    float acc = msg_b[tid];
    for (int k = 0; k < 256; ++k) acc += s_in[k] * msg_W[k*256 + tid];
    tabs[TAB_EM + t*256 + tid] = acc;
  } else {
    int t = b - 19;
    s_in[tid] = eemb[t*256 + tid];
    __syncthreads();
    float acc = 0.f;
    for (int k = 0; k < 256; ++k) acc += s_in[k] * att_W1[(512 + k)*256 + tid];
    tabs[TAB_EC + t*256 + tid] = acc;
  }
}

// ---------------- K0b: bf16 transposed weight copies ----------------
__global__ __launch_bounds__(256) void k_prep(
    const float* __restrict__ msg_W, const float* __restrict__ att_W1,
    const float* __restrict__ up_W1, const float* __restrict__ up_W2,
    unsigned short* __restrict__ WpreT, unsigned short* __restrict__ W1T,
    unsigned short* __restrict__ W2T)
{
  int b = blockIdx.x, tid = threadIdx.x;
  if (b < 768){
    int n = b;
    float v;
    if (n < 256)      v = msg_W[tid*256 + n];
    else if (n < 512) v = att_W1[tid*256 + (n - 256)];
    else              v = att_W1[(256 + tid)*256 + (n - 512)];
    WpreT[n*256 + tid] = f2bf(v);
  } else if (b < 1024){
    int n = b - 768;
    W1T[n*512 + tid]       = f2bf(up_W1[tid*256 + n]);
    W1T[n*512 + 256 + tid] = f2bf(up_W1[(256 + tid)*256 + n]);
  } else {
    int n = b - 1024;
    W2T[n*256 + tid] = f2bf(up_W2[tid*256 + n]);
  }
}

// ---------------- K1: P = X @ [msg_W | W1a | W1b]  (N x 768, bf16 out) ----------------
// MFMA 16x16x32 bf16. A-frag: row=lane&15, k=(lane>>4)*8+j. B-frag: col=lane&15, same k.
// C/D: col=lane&15, row=(lane>>4)*4+reg.
__global__ __launch_bounds__(256) void k_gemm_pre(
    const float* __restrict__ X, const unsigned short* __restrict__ WpreT,
    unsigned short* __restrict__ P)
{
  int wv = threadIdx.x >> 6, lane = threadIdx.x & 63;
  int tile = blockIdx.x*4 + wv;
  if (tile >= NN/16) return;
  int m0 = tile*16;
  int lo = lane & 15, hi = lane >> 4;
  bf16x8 a[8];
  const float* xrow = X + (size_t)(m0 + lo)*256 + hi*8;
  #pragma unroll
  for (int kc = 0; kc < 8; ++kc){
    float4 f0 = *(const float4*)(xrow + kc*32);
    float4 f1 = *(const float4*)(xrow + kc*32 + 4);
    bf16x8 v;
    v[0]=(__bf16)f0.x; v[1]=(__bf16)f0.y; v[2]=(__bf16)f0.z; v[3]=(__bf16)f0.w;
    v[4]=(__bf16)f1.x; v[5]=(__bf16)f1.y; v[6]=(__bf16)f1.z; v[7]=(__bf16)f1.w;
    a[kc] = v;
  }
  const unsigned short* bbase = WpreT + (size_t)lo*256 + hi*8;
  for (int nt = 0; nt < 48; ++nt){
    int n0 = nt*16;
    f32x4 acc = {0.f, 0.f, 0.f, 0.f};
    const unsigned short* bcol = bbase + (size_t)n0*256;
    #pragma unroll
    for (int kc = 0; kc < 8; ++kc){
      bf16x8 bfrag = *(const bf16x8*)(bcol + kc*32);
      acc = __builtin_amdgcn_mfma_f32_16x16x32_bf16(a[kc], bfrag, acc, 0, 0, 0);
    }
    unsigned short* prow = P + (size_t)(m0 + hi*4)*768 + n0 + lo;
    #pragma unroll
    for (int r = 0; r < 4; ++r) prow[(size_t)r*768] = f2bf(acc[r]);
  }
}

// ---------------- K2: fused per-edge kernel (1 wave / edge) ----------------
__global__ __launch_bounds__(256) void k_edges(
    const int* __restrict__ eidx, const int* __restrict__ etype,
    const unsigned short* __restrict__ P, const float* __restrict__ tabs,
    const float* __restrict__ attW2, const float* __restrict__ attb2,
    const float* __restrict__ escale,
    float* __restrict__ agg, float* __restrict__ deg)
{
  int e = blockIdx.x*4 + (threadIdx.x >> 6);
  if (e >= NE) return;
  int lane = threadIdx.x & 63;
  int src = eidx[e], dst = eidx[NE + e], et = etype[e];
  int c0 = lane*4;
  const unsigned short* ps = P + (size_t)src*768;
  const unsigned short* pd = P + (size_t)dst*768;
  ushort4 up1 = *(const ushort4*)(ps + 256 + c0);   // P1[src]
  ushort4 up2 = *(const ushort4*)(pd + 512 + c0);   // P2[dst]
  ushort4 um  = *(const ushort4*)(ps + c0);         // M[src]
  float4 tc = *(const float4*)(tabs + TAB_TASKC + c0);
  float4 ec = *(const float4*)(tabs + TAB_EC + et*256 + c0);
  float4 em = *(const float4*)(tabs + TAB_EM + et*256 + c0);
  float4 ms = *(const float4*)(tabs + TAB_MSG_SCALE + c0);
  float4 mb = *(const float4*)(tabs + TAB_MSG_BETA + c0);
  float4 w2 = *(const float4*)(attW2 + c0);
  float h0 = gelu_f(bf2f(up1.x) + bf2f(up2.x) + tc.x + ec.x);
  float h1 = gelu_f(bf2f(up1.y) + bf2f(up2.y) + tc.y + ec.y);
  float h2 = gelu_f(bf2f(up1.z) + bf2f(up2.z) + tc.z + ec.z);
  float h3 = gelu_f(bf2f(up1.w) + bf2f(up2.w) + tc.w + ec.w);
  float part = h0*w2.x + h1*w2.y + h2*w2.z + h3*w2.w;
  #pragma unroll
  for (int off = 32; off; off >>= 1) part += __shfl_xor(part, off);
  float w = 1.0f + escale[0] * tanhf(part + attb2[0]);
  float o0 = ((bf2f(um.x) + em.x)*ms.x + mb.x) * w;
  float o1 = ((bf2f(um.y) + em.y)*ms.y + mb.y) * w;
  float o2 = ((bf2f(um.z) + em.z)*ms.z + mb.z) * w;
  float o3 = ((bf2f(um.w) + em.w)*ms.w + mb.w) * w;
  float* ar = agg + (size_t)dst*256 + c0;
  unsafeAtomicAdd(ar + 0, o0);
  unsafeAtomicAdd(ar + 1, o1);
  unsafeAtomicAdd(ar + 2, o2);
  unsafeAtomicAdd(ar + 3, o3);
  if (lane == 0) unsafeAtomicAdd(deg + dst, w);
}

// ---------------- K3: fused update MLP + residual + LayerNorm (16 rows / block) ----------------
__global__ __launch_bounds__(256) void k_final(
    const float* __restrict__ X, const float* __restrict__ agg,
    const float* __restrict__ deg, const float* __restrict__ tabs,
    const unsigned short* __restrict__ W1T, const unsigned short* __restrict__ W2T,
    const float* __restrict__ up_b1, const float* __restrict__ up_b2,
    const float* __restrict__ ln_g, const float* __restrict__ ln_b,
    float* __restrict__ out)
{
  __shared__ unsigned short s_upd[16*512];  // bf16, XOR-swizzled (elem ^= (row&7)<<3)
  __shared__ unsigned short s_H[16*256];    // bf16, XOR-swizzled
  __shared__ float s_y[16*256];
  __shared__ float s_mu[16], s_rs[16];
  int m0 = blockIdx.x*16;
  int tid = threadIdx.x;
  // stage upd_in = [x | (agg/deg)*upd_scale + upd_beta] as bf16
  for (int i = tid; i < 16*512; i += 256){
    int rr = i >> 9, c = i & 511;
    float v;
    if (c < 256) v = X[(size_t)(m0 + rr)*256 + c];
    else {
      int cc = c - 256;
      float d = fmaxf(deg[m0 + rr], 1.0f);
      v = agg[(size_t)(m0 + rr)*256 + cc] / d;
      v = v * tabs[TAB_UPD_SCALE + cc] + tabs[TAB_UPD_BETA + cc];
    }
    s_upd[(rr << 9) | (c ^ ((rr & 7) << 3))] = f2bf(v);
  }
  __syncthreads();
  int wv = tid >> 6, lane = tid & 63, lo = lane & 15, hi = lane >> 4;
  // GEMM1: H = gelu(upd_in @ up_W1 + b1); wave wv covers cols [wv*64, wv*64+64)
  f32x4 acc[4];
  #pragma unroll
  for (int t = 0; t < 4; ++t){
    float b = up_b1[wv*64 + t*16 + lo];
    acc[t] = (f32x4){b, b, b, b};
  }
  #pragma unroll
  for (int kc = 0; kc < 16; ++kc){
    int ke = kc*32 + hi*8;
    bf16x8 af = *(const bf16x8*)(s_upd + ((lo << 9) | (ke ^ ((lo & 7) << 3))));
    #pragma unroll
    for (int t = 0; t < 4; ++t){
      int n = wv*64 + t*16 + lo;
      bf16x8 bf = *(const bf16x8*)(W1T + (size_t)n*512 + ke);
      acc[t] = __builtin_amdgcn_mfma_f32_16x16x32_bf16(af, bf, acc[t], 0, 0, 0);
    }
  }
  #pragma unroll
  for (int t = 0; t < 4; ++t){
    #pragma unroll
    for (int r = 0; r < 4; ++r){
      int row = hi*4 + r, n = wv*64 + t*16 + lo;
      s_H[(row << 8) | (n ^ ((row & 7) << 3))] = f2bf(gelu_f(acc[t][r]));
    }
  }
  __syncthreads();
  // GEMM2: updated = H @ up_W2 + b2
  f32x4 acc2[4];
  #pragma unroll
  for (int t = 0; t < 4; ++t){
    float b = up_b2[wv*64 + t*16 + lo];
    acc2[t] = (f32x4){b, b, b, b};
  }
  #pragma unroll
  for (int kc = 0; kc < 8; ++kc){
    int ke = kc*32 + hi*8;
    bf16x8 af = *(const bf16x8*)(s_H + ((lo << 8) | (ke ^ ((lo & 7) << 3))));
    #pragma unroll
    for (int t = 0; t < 4; ++t){
      int n = wv*64 + t*16 + lo;
      bf16x8 bf = *(const bf16x8*)(W2T + (size_t)n*256 + ke);
      acc2[t] = __builtin_amdgcn_mfma_f32_16x16x32_bf16(af, bf, acc2[t], 0, 0, 0);
    }
  }
  #pragma unroll
  for (int t = 0; t < 4; ++t){
    #pragma unroll
    for (int r = 0; r < 4; ++r){
      int row = hi*4 + r, n = wv*64 + t*16 + lo;
      s_y[row*256 + n] = X[(size_t)(m0 + row)*256 + n] + acc2[t][r];
    }
  }
  __syncthreads();
  // LayerNorm: 16 threads per row
  {
    int r = tid >> 4, g = tid & 15;
    float sum = 0.f, sq = 0.f;
    for (int c = g; c < 256; c += 16){
      float v = s_y[r*256 + c];
      sum += v; sq += v*v;
    }
    #pragma unroll
    for (int off = 8; off; off >>= 1){
      sum += __shfl_xor(sum, off, 16);
      sq  += __shfl_xor(sq,  off, 16);
    }
    if (g == 0){
      float mu = sum * (1.0f/256.0f);
      float var = sq * (1.0f/256.0f) - mu*mu;
      s_mu[r] = mu;
      s_rs[r] = rsqrtf(var + 1e-5f);
    }
  }
  __syncthreads();
  for (int i = tid; i < 4096; i += 256){
    int rr = i >> 8, c = i & 255;
    out[(size_t)(m0 + rr)*256 + c] = (s_y[i] - s_mu[rr]) * s_rs[rr] * ln_g[c] + ln_b[c];
  }
}

extern "C" void kernel_launch(void* const* d_in, const int* in_sizes, int n_in,
                              void* d_out, int out_size, void* d_ws, size_t ws_size,
                              hipStream_t stream)
{
  (void)in_sizes; (void)n_in; (void)out_size;
  if (ws_size < WS_NEED) return;  // fail loudly via validation rather than corrupt memory
  const float* X      = (const float*)d_in[0];
  const int*   eidx   = (const int*)d_in[1];
  const int*   etype  = (const int*)d_in[2];
  const float* task   = (const float*)d_in[3];
  const float* eemb   = (const float*)d_in[4];
  const float* msg_W  = (const float*)d_in[5];
  const float* msg_b  = (const float*)d_in[6];
  const float* att_W1 = (const float*)d_in[7];
  const float* att_b1 = (const float*)d_in[8];
  const float* att_W2 = (const float*)d_in[9];
  const float* att_b2 = (const float*)d_in[10];
  const float* escale = (const float*)d_in[11];
  const float* ma_W1  = (const float*)d_in[12];
  const float* ma_b1  = (const float*)d_in[13];
  const float* ma_W2  = (const float*)d_in[14];
  const float* ma_b2  = (const float*)d_in[15];
  const float* up_W1  = (const float*)d_in[16];
  const float* up_b1  = (const float*)d_in[17];
  const float* up_W2  = (const float*)d_in[18];
  const float* up_b2  = (const float*)d_in[19];
  const float* ua_W1  = (const float*)d_in[20];
  const float* ua_b1  = (const float*)d_in[21];
  const float* ua_W2  = (const float*)d_in[22];
  const float* ua_b2  = (const float*)d_in[23];
  const float* ln_g   = (const float*)d_in[24];
  const float* ln_b   = (const float*)d_in[25];
  char* ws = (char*)d_ws;
  float* tabs = (float*)ws;
  unsigned short* WpreT = (unsigned short*)(ws + OFF_WPRET);
  unsigned short* W1T   = (unsigned short*)(ws + OFF_W1T);
  unsigned short* W2T   = (unsigned short*)(ws + OFF_W2T);
  unsigned short* P     = (unsigned short*)(ws + OFF_P);
  float* agg = (float*)(ws + OFF_AGG);
  float* deg = (float*)(ws + OFF_DEG);
  float* out = (float*)d_out;

  hipMemsetAsync(ws + OFF_AGG, 0, (OFF_DEG - OFF_AGG) + (size_t)NN*4, stream);
  k_tables<<<35, 256, 0, stream>>>(task, eemb, msg_W, msg_b, att_W1, att_b1,
                                   ma_W1, ma_b1, ma_W2, ma_b2,
                                   ua_W1, ua_b1, ua_W2, ua_b2, tabs);
  k_prep<<<1280, 256, 0, stream>>>(msg_W, att_W1, up_W1, up_W2, WpreT, W1T, W2T);
  k_gemm_pre<<<(NN/16 + 3)/4, 256, 0, stream>>>(X, WpreT, P);
  k_edges<<<NE/4, 256, 0, stream>>>(eidx, etype, P, tabs, att_W2, att_b2, escale, agg, deg);
  k_final<<<NN/16, 256, 0, stream>>>(X, agg, deg, tabs, W1T, W2T, up_b1, up_b2, ln_g, ln_b, out);
}

// Round 3
// 426.912 us; speedup vs baseline: 2.1593x; 2.1593x over previous
//
#include <hip/hip_runtime.h>
#include <hip/hip_bf16.h>

#define NN 20000
#define NE 200000

typedef __bf16 bf16x8 __attribute__((ext_vector_type(8)));
typedef float f32x4 __attribute__((ext_vector_type(4)));

// ---- workspace layout (bytes) ----
constexpr int TAB_MSG_SCALE = 0;      // f32 element offsets within tabs
constexpr int TAB_MSG_BETA  = 256;
constexpr int TAB_UPD_SCALE = 512;
constexpr int TAB_UPD_BETA  = 768;
constexpr int TAB_TASKC     = 1024;   // task @ att_W1[768:1024] + att_b1
constexpr int TAB_EM        = 1280;   // 16*256  e@msg_W + msg_b
constexpr int TAB_EC        = 1280 + 4096; // 16*256  e@att_W1[512:768]
constexpr size_t OFF_WPRET = 40960;    // u16[768*256] n-major
constexpr size_t OFF_W1T   = 434176;   // u16[256*512]
constexpr size_t OFF_W2T   = 696320;   // u16[256*256]
constexpr size_t OFF_CNT   = 827392;   // i32[NN]
constexpr size_t OFF_PTRS  = 907392;   // i32[NN+1]
constexpr size_t OFF_PWORK = 987648;   // i32[NN]
constexpr size_t OFF_SRC   = 1067648;  // i32[NE]
constexpr size_t OFF_ET    = 1867648;  // i32[NE]
constexpr size_t OFF_WE    = 2667648;  // f32[NE]
constexpr size_t OFF_MF    = 3467776;  // f32[NN*256]   M = X@msg_W (f32!)
constexpr size_t OFF_P     = 23947776; // u16[NN*512]   [P1 | P2] bf16
constexpr size_t WS_NEED   = 44427776;

__device__ __forceinline__ float bf2f(unsigned short u){
  union { unsigned int i; float f; } v; v.i = ((unsigned int)u) << 16; return v.f;
}
__device__ __forceinline__ unsigned short f2bf(float f){
  __bf16 h = (__bf16)f; unsigned short u; __builtin_memcpy(&u, &h, 2); return u;
}
__device__ __forceinline__ float gelu_f(float x){
  return 0.5f * x * (1.0f + erff(x * 0.70710678118654752f));
}

// ---------------- K0: tiny tables (proven round-1) ----------------
__global__ __launch_bounds__(256) void k_tables(
    const float* __restrict__ task, const float* __restrict__ eemb,
    const float* __restrict__ msg_W, const float* __restrict__ msg_b,
    const float* __restrict__ att_W1, const float* __restrict__ att_b1,
    const float* __restrict__ ma_W1, const float* __restrict__ ma_b1,
    const float* __restrict__ ma_W2, const float* __restrict__ ma_b2,
    const float* __restrict__ ua_W1, const float* __restrict__ ua_b1,
    const float* __restrict__ ua_W2, const float* __restrict__ ua_b2,
    float* __restrict__ tabs)
{
  __shared__ float s_in[512];
  __shared__ float s_h[512];
  int b = blockIdx.x, tid = threadIdx.x;
  if (b < 2){
    const float* W1 = b ? ua_W1 : ma_W1;  const float* b1 = b ? ua_b1 : ma_b1;
    const float* W2 = b ? ua_W2 : ma_W2;  const float* b2 = b ? ua_b2 : ma_b2;
    s_in[tid] = task[tid];
    __syncthreads();
    #pragma unroll
    for (int jj = 0; jj < 2; ++jj){
      int j = tid + jj*256;
      float acc = b1[j];
      for (int k = 0; k < 256; ++k) acc += s_in[k] * W1[k*512 + j];
      s_h[j] = gelu_f(acc);
    }
    __syncthreads();
    float o[2];
    #pragma unroll
    for (int jj = 0; jj < 2; ++jj){
      int j = tid + jj*256;
      float acc = b2[j];
      for (int k = 0; k < 512; ++k) acc += s_h[k] * W2[k*512 + j];
      o[jj] = acc;
    }
    float* scale = tabs + (b ? TAB_UPD_SCALE : TAB_MSG_SCALE);
    float* beta  = tabs + (b ? TAB_UPD_BETA  : TAB_MSG_BETA);
    scale[tid] = 1.0f + 0.5f * tanhf(o[0]);
    beta[tid]  = o[1];
  } else if (b == 2){
    s_in[tid] = task[tid];
    __syncthreads();
    float acc = att_b1[tid];
    for (int k = 0; k < 256; ++k) acc += s_in[k] * att_W1[(768 + k)*256 + tid];
    tabs[TAB_TASKC + tid] = acc;
  } else if (b < 19){
    int t = b - 3;
    s_in[tid] = eemb[t*256 + tid];
    __syncthreads();
    float acc = msg_b[tid];
    for (int k = 0; k < 256; ++k) acc += s_in[k] * msg_W[k*256 + tid];
    tabs[TAB_EM + t*256 + tid] = acc;
  } else {
    int t = b - 19;
    s_in[tid] = eemb[t*256 + tid];
    __syncthreads();
    float acc = 0.f;
    for (int k = 0; k < 256; ++k) acc += s_in[k] * att_W1[(512 + k)*256 + tid];
    tabs[TAB_EC + t*256 + tid] = acc;
  }
}

// ---------------- K0b: bf16 transposed weight copies (proven round-1) ----------------
__global__ __launch_bounds__(256) void k_prep(
    const float* __restrict__ msg_W, const float* __restrict__ att_W1,
    const float* __restrict__ up_W1, const float* __restrict__ up_W2,
    unsigned short* __restrict__ WpreT, unsigned short* __restrict__ W1T,
    unsigned short* __restrict__ W2T)
{
  int b = blockIdx.x, tid = threadIdx.x;
  if (b < 768){
    int n = b;
    float v;
    if (n < 256)      v = msg_W[tid*256 + n];
    else if (n < 512) v = att_W1[tid*256 + (n - 256)];
    else              v = att_W1[(256 + tid)*256 + (n - 512)];
    WpreT[n*256 + tid] = f2bf(v);
  } else if (b < 1024){
    int n = b - 768;
    W1T[n*512 + tid]       = f2bf(up_W1[tid*256 + n]);
    W1T[n*512 + 256 + tid] = f2bf(up_W1[(256 + tid)*256 + n]);
  } else {
    int n = b - 1024;
    W2T[n*256 + tid] = f2bf(up_W2[tid*256 + n]);
  }
}

// ---------------- K1: [Mf | P] = X @ [msg_W | W1a | W1b]  (proven round-1 structure) ----------------
// wave = one 16-row tile; B read directly from global WpreT.
// Mf (cols 0..255) stored f32; P (cols 256..767 -> P cols 0..511) stored bf16.
__global__ __launch_bounds__(256) void k_gemm_pre(
    const float* __restrict__ X, const unsigned short* __restrict__ WpreT,
    float* __restrict__ Mf, unsigned short* __restrict__ P)
{
  int wv = threadIdx.x >> 6, lane = threadIdx.x & 63;
  int tile = blockIdx.x*4 + wv;
  if (tile >= NN/16) return;
  int m0 = tile*16;
  int lo = lane & 15, hi = lane >> 4;
  bf16x8 a[8];
  const float* xrow = X + (size_t)(m0 + lo)*256 + hi*8;
  #pragma unroll
  for (int kc = 0; kc < 8; ++kc){
    float4 f0 = *(const float4*)(xrow + kc*32);
    float4 f1 = *(const float4*)(xrow + kc*32 + 4);
    bf16x8 v;
    v[0]=(__bf16)f0.x; v[1]=(__bf16)f0.y; v[2]=(__bf16)f0.z; v[3]=(__bf16)f0.w;
    v[4]=(__bf16)f1.x; v[5]=(__bf16)f1.y; v[6]=(__bf16)f1.z; v[7]=(__bf16)f1.w;
    a[kc] = v;
  }
  const unsigned short* bbase = WpreT + (size_t)lo*256 + hi*8;
  for (int nt = 0; nt < 48; ++nt){
    int n0 = nt*16;
    f32x4 acc = {0.f, 0.f, 0.f, 0.f};
    const unsigned short* bcol = bbase + (size_t)n0*256;
    #pragma unroll
    for (int kc = 0; kc < 8; ++kc){
      bf16x8 bfrag = *(const bf16x8*)(bcol + kc*32);
      acc = __builtin_amdgcn_mfma_f32_16x16x32_bf16(a[kc], bfrag, acc, 0, 0, 0);
    }
    if (nt < 16){
      float* mrow = Mf + (size_t)(m0 + hi*4)*256 + n0 + lo;
      #pragma unroll
      for (int r = 0; r < 4; ++r) mrow[(size_t)r*256] = acc[r];
    } else {
      unsigned short* prow = P + (size_t)(m0 + hi*4)*512 + (n0 - 256) + lo;
      #pragma unroll
      for (int r = 0; r < 4; ++r) prow[(size_t)r*512] = f2bf(acc[r]);
    }
  }
}

// ---------------- K2a: in-degree histogram ----------------
__global__ __launch_bounds__(256) void k_hist(
    const int* __restrict__ eidx, int* __restrict__ cnt)
{
  int e = blockIdx.x*256 + threadIdx.x;
  if (e < NE) atomicAdd(&cnt[eidx[NE + e]], 1);
}

// ---------------- K2b: exclusive prefix sum (single block) ----------------
__global__ __launch_bounds__(1024) void k_scan(
    const int* __restrict__ cnt, int* __restrict__ ptrs, int* __restrict__ pwork)
{
  __shared__ int s[1024];
  int tid = threadIdx.x;
  int carry = 0;
  for (int base = 0; base < NN; base += 1024){
    int i = base + tid;
    int v = (i < NN) ? cnt[i] : 0;
    __syncthreads();
    s[tid] = v;
    __syncthreads();
    #pragma unroll
    for (int off = 1; off < 1024; off <<= 1){
      int t = (tid >= off) ? s[tid - off] : 0;
      __syncthreads();
      s[tid] += t;
      __syncthreads();
    }
    int excl = s[tid] - v;
    if (i < NN){
      ptrs[i]  = carry + excl;
      pwork[i] = carry + excl;
    }
    carry += s[1023];
    __syncthreads();
  }
  if (tid == 0) ptrs[NN] = carry;
}

// ---------------- K3: per-edge attention weight + CSR scatter (plain arrays) ----------------
__global__ __launch_bounds__(256) void k_att_csr(
    const int* __restrict__ eidx, const int* __restrict__ etype,
    const unsigned short* __restrict__ P, const float* __restrict__ tabs,
    const float* __restrict__ attW2, const float* __restrict__ attb2,
    const float* __restrict__ escale,
    int* __restrict__ pwork,
    int* __restrict__ srcbuf, int* __restrict__ etbuf, float* __restrict__ wbuf)
{
  int e = blockIdx.x*4 + (threadIdx.x >> 6);
  if (e >= NE) return;
  int lane = threadIdx.x & 63;
  int src = eidx[e], dst = eidx[NE + e], et = etype[e];
  int c0 = lane*4;
  const unsigned short* ps = P + (size_t)src*512;
  const unsigned short* pd = P + (size_t)dst*512;
  ushort4 up1 = *(const ushort4*)(ps + c0);         // P1[src]
  ushort4 up2 = *(const ushort4*)(pd + 256 + c0);   // P2[dst]
  float4 tc = *(const float4*)(tabs + TAB_TASKC + c0);
  float4 ec = *(const float4*)(tabs + TAB_EC + et*256 + c0);
  float4 w2 = *(const float4*)(attW2 + c0);
  float h0 = gelu_f(bf2f(up1.x) + bf2f(up2.x) + tc.x + ec.x);
  float h1 = gelu_f(bf2f(up1.y) + bf2f(up2.y) + tc.y + ec.y);
  float h2 = gelu_f(bf2f(up1.z) + bf2f(up2.z) + tc.z + ec.z);
  float h3 = gelu_f(bf2f(up1.w) + bf2f(up2.w) + tc.w + ec.w);
  float part = h0*w2.x + h1*w2.y + h2*w2.z + h3*w2.w;
  #pragma unroll
  for (int off = 32; off; off >>= 1) part += __shfl_xor(part, off);
  float w = 1.0f + escale[0] * tanhf(part + attb2[0]);
  if (lane == 0){
    int pos = atomicAdd(&pwork[dst], 1);
    srcbuf[pos] = src;
    etbuf[pos]  = et;
    wbuf[pos]   = w;
  }
}

// ---------------- K4: gather-aggregate + update MLP + residual + LayerNorm ----------------
__global__ __launch_bounds__(256) void k_final(
    const float* __restrict__ X, const int* __restrict__ ptrs,
    const int* __restrict__ srcbuf, const int* __restrict__ etbuf,
    const float* __restrict__ wbuf, const float* __restrict__ Mf,
    const float* __restrict__ tabs,
    const unsigned short* __restrict__ W1T, const unsigned short* __restrict__ W2T,
    const float* __restrict__ up_b1, const float* __restrict__ up_b2,
    const float* __restrict__ ln_g, const float* __restrict__ ln_b,
    float* __restrict__ out)
{
  __shared__ float em_s[16*256];
  __shared__ unsigned short s_upd[16*512];  // bf16, XOR-swizzled (elem ^= (row&7)<<3)
  __shared__ unsigned short s_H[16*256];    // bf16, XOR-swizzled
  __shared__ float s_y[16*256];
  __shared__ float s_mu[16], s_rs[16];
  int m0 = blockIdx.x*16;
  int tid = threadIdx.x;
  int wv = tid >> 6, lane = tid & 63;

  // stage em table (scalar, proven pattern)
  for (int i = tid; i < 4096; i += 256) em_s[i] = tabs[TAB_EM + i];
  // stage X -> s_upd[:, 0:256] (bf16, swizzled, scalar — proven round-1 pattern)
  for (int i = tid; i < 16*256; i += 256){
    int rr = i >> 8, c = i & 255;
    s_upd[(rr << 9) | (c ^ ((rr & 7) << 3))] = f2bf(X[(size_t)(m0 + rr)*256 + c]);
  }
  __syncthreads();

  // gather-aggregate: wave wv handles rows 4wv..4wv+3; lane owns 4 dims
  {
    int c0 = lane*4;
    float4 ms = *(const float4*)(tabs + TAB_MSG_SCALE + c0);
    float4 mb = *(const float4*)(tabs + TAB_MSG_BETA  + c0);
    float4 us = *(const float4*)(tabs + TAB_UPD_SCALE + c0);
    float4 ub = *(const float4*)(tabs + TAB_UPD_BETA  + c0);
    for (int rr = 0; rr < 4; ++rr){
      int node = m0 + wv*4 + rr;
      int start = ptrs[node], end = ptrs[node + 1];
      float ax = 0.f, ay = 0.f, az = 0.f, aw = 0.f, W = 0.f;
      for (int i = start; i < end; ++i){
        int   src = srcbuf[i];     // wave-uniform
        int   et  = etbuf[i];
        float w   = wbuf[i];
        float4 mm = *(const float4*)(Mf + (size_t)src*256 + c0);
        float4 ev = *(const float4*)(em_s + et*256 + c0);
        ax += w*(mm.x + ev.x);
        ay += w*(mm.y + ev.y);
        az += w*(mm.z + ev.z);
        aw += w*(mm.w + ev.w);
        W += w;
      }
      float d = fmaxf(W, 1.0f), rd = 1.0f / d;
      float vx = (ms.x*ax + mb.x*W)*rd*us.x + ub.x;
      float vy = (ms.y*ay + mb.y*W)*rd*us.y + ub.y;
      float vz = (ms.z*az + mb.z*W)*rd*us.z + ub.z;
      float vw = (ms.w*aw + mb.w*W)*rd*us.w + ub.w;
      int r = wv*4 + rr;
      int swz = (r & 7) << 3;
      s_upd[(r << 9) | ((256 + c0 + 0) ^ swz)] = f2bf(vx);
      s_upd[(r << 9) | ((256 + c0 + 1) ^ swz)] = f2bf(vy);
      s_upd[(r << 9) | ((256 + c0 + 2) ^ swz)] = f2bf(vz);
      s_upd[(r << 9) | ((256 + c0 + 3) ^ swz)] = f2bf(vw);
    }
  }
  __syncthreads();

  int lo = lane & 15, hi = lane >> 4;
  // GEMM1: H = gelu(upd_in @ up_W1 + b1); wave wv covers cols [wv*64, wv*64+64)
  f32x4 acc[4];
  #pragma unroll
  for (int t = 0; t < 4; ++t){
    float b = up_b1[wv*64 + t*16 + lo];
    acc[t] = (f32x4){b, b, b, b};
  }
  #pragma unroll
  for (int kc = 0; kc < 16; ++kc){
    int ke = kc*32 + hi*8;
    bf16x8 af = *(const bf16x8*)(s_upd + ((lo << 9) | (ke ^ ((lo & 7) << 3))));
    #pragma unroll
    for (int t = 0; t < 4; ++t){
      int n = wv*64 + t*16 + lo;
      bf16x8 bf = *(const bf16x8*)(W1T + (size_t)n*512 + ke);
      acc[t] = __builtin_amdgcn_mfma_f32_16x16x32_bf16(af, bf, acc[t], 0, 0, 0);
    }
  }
  #pragma unroll
  for (int t = 0; t < 4; ++t){
    #pragma unroll
    for (int r = 0; r < 4; ++r){
      int row = hi*4 + r, n = wv*64 + t*16 + lo;
      s_H[(row << 8) | (n ^ ((row & 7) << 3))] = f2bf(gelu_f(acc[t][r]));
    }
  }
  __syncthreads();
  // GEMM2: updated = H @ up_W2 + b2
  f32x4 acc2[4];
  #pragma unroll
  for (int t = 0; t < 4; ++t){
    float b = up_b2[wv*64 + t*16 + lo];
    acc2[t] = (f32x4){b, b, b, b};
  }
  #pragma unroll
  for (int kc = 0; kc < 8; ++kc){
    int ke = kc*32 + hi*8;
    bf16x8 af = *(const bf16x8*)(s_H + ((lo << 8) | (ke ^ ((lo & 7) << 3))));
    #pragma unroll
    for (int t = 0; t < 4; ++t){
      int n = wv*64 + t*16 + lo;
      bf16x8 bf = *(const bf16x8*)(W2T + (size_t)n*256 + ke);
      acc2[t] = __builtin_amdgcn_mfma_f32_16x16x32_bf16(af, bf, acc2[t], 0, 0, 0);
    }
  }
  #pragma unroll
  for (int t = 0; t < 4; ++t){
    #pragma unroll
    for (int r = 0; r < 4; ++r){
      int row = hi*4 + r, n = wv*64 + t*16 + lo;
      s_y[row*256 + n] = X[(size_t)(m0 + row)*256 + n] + acc2[t][r];
    }
  }
  __syncthreads();
  // LayerNorm
  {
    int r = tid >> 4, g = tid & 15;
    float sum = 0.f, sq = 0.f;
    for (int c = g; c < 256; c += 16){
      float v = s_y[r*256 + c];
      sum += v; sq += v*v;
    }
    #pragma unroll
    for (int off = 8; off; off >>= 1){
      sum += __shfl_xor(sum, off, 16);
      sq  += __shfl_xor(sq,  off, 16);
    }
    if (g == 0){
      float mu = sum * (1.0f/256.0f);
      float var = sq * (1.0f/256.0f) - mu*mu;
      s_mu[r] = mu;
      s_rs[r] = rsqrtf(var + 1e-5f);
    }
  }
  __syncthreads();
  for (int i = tid; i < 4096; i += 256){
    int rr = i >> 8, c = i & 255;
    out[(size_t)(m0 + rr)*256 + c] = (s_y[i] - s_mu[rr]) * s_rs[rr] * ln_g[c] + ln_b[c];
  }
}

extern "C" void kernel_launch(void* const* d_in, const int* in_sizes, int n_in,
                              void* d_out, int out_size, void* d_ws, size_t ws_size,
                              hipStream_t stream)
{
  (void)in_sizes; (void)n_in; (void)out_size;
  if (ws_size < WS_NEED) return;
  const float* X      = (const float*)d_in[0];
  const int*   eidx   = (const int*)d_in[1];
  const int*   etype  = (const int*)d_in[2];
  const float* task   = (const float*)d_in[3];
  const float* eemb   = (const float*)d_in[4];
  const float* msg_W  = (const float*)d_in[5];
  const float* msg_b  = (const float*)d_in[6];
  const float* att_W1 = (const float*)d_in[7];
  const float* att_b1 = (const float*)d_in[8];
  const float* att_W2 = (const float*)d_in[9];
  const float* att_b2 = (const float*)d_in[10];
  const float* escale = (const float*)d_in[11];
  const float* ma_W1  = (const float*)d_in[12];
  const float* ma_b1  = (const float*)d_in[13];
  const float* ma_W2  = (const float*)d_in[14];
  const float* ma_b2  = (const float*)d_in[15];
  const float* up_W1  = (const float*)d_in[16];
  const float* up_b1  = (const float*)d_in[17];
  const float* up_W2  = (const float*)d_in[18];
  const float* up_b2  = (const float*)d_in[19];
  const float* ua_W1  = (const float*)d_in[20];
  const float* ua_b1  = (const float*)d_in[21];
  const float* ua_W2  = (const float*)d_in[22];
  const float* ua_b2  = (const float*)d_in[23];
  const float* ln_g   = (const float*)d_in[24];
  const float* ln_b   = (const float*)d_in[25];
  char* ws = (char*)d_ws;
  float* tabs = (float*)ws;
  unsigned short* WpreT = (unsigned short*)(ws + OFF_WPRET);
  unsigned short* W1T   = (unsigned short*)(ws + OFF_W1T);
  unsigned short* W2T   = (unsigned short*)(ws + OFF_W2T);
  int*   cnt    = (int*)(ws + OFF_CNT);
  int*   ptrs   = (int*)(ws + OFF_PTRS);
  int*   pwork  = (int*)(ws + OFF_PWORK);
  int*   srcbuf = (int*)(ws + OFF_SRC);
  int*   etbuf  = (int*)(ws + OFF_ET);
  float* wbuf   = (float*)(ws + OFF_WE);
  float* Mf     = (float*)(ws + OFF_MF);
  unsigned short* P = (unsigned short*)(ws + OFF_P);
  float* out = (float*)d_out;

  hipMemsetAsync(cnt, 0, (size_t)NN*4, stream);
  k_tables<<<35, 256, 0, stream>>>(task, eemb, msg_W, msg_b, att_W1, att_b1,
                                   ma_W1, ma_b1, ma_W2, ma_b2,
                                   ua_W1, ua_b1, ua_W2, ua_b2, tabs);
  k_prep<<<1280, 256, 0, stream>>>(msg_W, att_W1, up_W1, up_W2, WpreT, W1T, W2T);
  k_gemm_pre<<<(NN/16 + 3)/4, 256, 0, stream>>>(X, WpreT, Mf, P);
  k_hist<<<(NE + 255)/256, 256, 0, stream>>>(eidx, cnt);
  k_scan<<<1, 1024, 0, stream>>>(cnt, ptrs, pwork);
  k_att_csr<<<NE/4, 256, 0, stream>>>(eidx, etype, P, tabs, att_W2, att_b2,
                                      escale, pwork, srcbuf, etbuf, wbuf);
  k_final<<<NN/16, 256, 0, stream>>>(X, ptrs, srcbuf, etbuf, wbuf, Mf, tabs,
                                     W1T, W2T, up_b1, up_b2, ln_g, ln_b, out);
}

// Round 4
// 324.511 us; speedup vs baseline: 2.8406x; 1.3156x over previous
//
#include <hip/hip_runtime.h>
#include <hip/hip_bf16.h>

#define NN 20000
#define NE 200000

typedef __bf16 bf16x8 __attribute__((ext_vector_type(8)));
typedef float f32x4 __attribute__((ext_vector_type(4)));

// ---- workspace layout (bytes) ----
constexpr int TAB_MSG_SCALE = 0;      // f32 element offsets within tabs
constexpr int TAB_MSG_BETA  = 256;
constexpr int TAB_UPD_SCALE = 512;
constexpr int TAB_UPD_BETA  = 768;
constexpr int TAB_TASKC     = 1024;   // task @ att_W1[768:1024] + att_b1
constexpr int TAB_EM        = 1280;   // 16*256  e@msg_W + msg_b
constexpr int TAB_EC        = 1280 + 4096; // 16*256  e@att_W1[512:768]
constexpr size_t OFF_WPRET = 40960;    // u16[768*256] n-major
constexpr size_t OFF_W1T   = 434176;   // u16[256*512]
constexpr size_t OFF_W2T   = 696320;   // u16[256*256]
constexpr size_t OFF_CNT   = 827392;   // i32[NN]
constexpr size_t OFF_PTRS  = 907392;   // i32[NN+1]
constexpr size_t OFF_PWORK = 987648;   // i32[NN]
constexpr size_t OFF_SRCET = 1067648;  // u32[NE]  src | et<<16 (CSR order)
constexpr size_t OFF_WE    = 1867648;  // f32[NE]  w (CSR order)
constexpr size_t OFF_MF    = 2667648;  // f32[NN*256]   M = X@msg_W (f32)
constexpr size_t OFF_P     = 23147648; // u16[NN*512]   [P1 | P2+tc] bf16
constexpr size_t WS_NEED   = 43627648;

__device__ __forceinline__ float bf2f(unsigned short u){
  union { unsigned int i; float f; } v; v.i = ((unsigned int)u) << 16; return v.f;
}
__device__ __forceinline__ unsigned short f2bf(float f){
  __bf16 h = (__bf16)f; unsigned short u; __builtin_memcpy(&u, &h, 2); return u;
}
__device__ __forceinline__ float gelu_f(float x){
  return 0.5f * x * (1.0f + erff(x * 0.70710678118654752f));
}

// ---------------- K0: tiny tables (proven) ----------------
__global__ __launch_bounds__(256) void k_tables(
    const float* __restrict__ task, const float* __restrict__ eemb,
    const float* __restrict__ msg_W, const float* __restrict__ msg_b,
    const float* __restrict__ att_W1, const float* __restrict__ att_b1,
    const float* __restrict__ ma_W1, const float* __restrict__ ma_b1,
    const float* __restrict__ ma_W2, const float* __restrict__ ma_b2,
    const float* __restrict__ ua_W1, const float* __restrict__ ua_b1,
    const float* __restrict__ ua_W2, const float* __restrict__ ua_b2,
    float* __restrict__ tabs)
{
  __shared__ float s_in[512];
  __shared__ float s_h[512];
  int b = blockIdx.x, tid = threadIdx.x;
  if (b < 2){
    const float* W1 = b ? ua_W1 : ma_W1;  const float* b1 = b ? ua_b1 : ma_b1;
    const float* W2 = b ? ua_W2 : ma_W2;  const float* b2 = b ? ua_b2 : ma_b2;
    s_in[tid] = task[tid];
    __syncthreads();
    #pragma unroll
    for (int jj = 0; jj < 2; ++jj){
      int j = tid + jj*256;
      float acc = b1[j];
      for (int k = 0; k < 256; ++k) acc += s_in[k] * W1[k*512 + j];
      s_h[j] = gelu_f(acc);
    }
    __syncthreads();
    float o[2];
    #pragma unroll
    for (int jj = 0; jj < 2; ++jj){
      int j = tid + jj*256;
      float acc = b2[j];
      for (int k = 0; k < 512; ++k) acc += s_h[k] * W2[k*512 + j];
      o[jj] = acc;
    }
    float* scale = tabs + (b ? TAB_UPD_SCALE : TAB_MSG_SCALE);
    float* beta  = tabs + (b ? TAB_UPD_BETA  : TAB_MSG_BETA);
    scale[tid] = 1.0f + 0.5f * tanhf(o[0]);
    beta[tid]  = o[1];
  } else if (b == 2){
    s_in[tid] = task[tid];
    __syncthreads();
    float acc = att_b1[tid];
    for (int k = 0; k < 256; ++k) acc += s_in[k] * att_W1[(768 + k)*256 + tid];
    tabs[TAB_TASKC + tid] = acc;
  } else if (b < 19){
    int t = b - 3;
    s_in[tid] = eemb[t*256 + tid];
    __syncthreads();
    float acc = msg_b[tid];
    for (int k = 0; k < 256; ++k) acc += s_in[k] * msg_W[k*256 + tid];
    tabs[TAB_EM + t*256 + tid] = acc;
  } else {
    int t = b - 19;
    s_in[tid] = eemb[t*256 + tid];
    __syncthreads();
    float acc = 0.f;
    for (int k = 0; k < 256; ++k) acc += s_in[k] * att_W1[(512 + k)*256 + tid];
    tabs[TAB_EC + t*256 + tid] = acc;
  }
}

// ---------------- K0b: bf16 transposed weight copies (proven) ----------------
__global__ __launch_bounds__(256) void k_prep(
    const float* __restrict__ msg_W, const float* __restrict__ att_W1,
    const float* __restrict__ up_W1, const float* __restrict__ up_W2,
    unsigned short* __restrict__ WpreT, unsigned short* __restrict__ W1T,
    unsigned short* __restrict__ W2T)
{
  int b = blockIdx.x, tid = threadIdx.x;
  if (b < 768){
    int n = b;
    float v;
    if (n < 256)      v = msg_W[tid*256 + n];
    else if (n < 512) v = att_W1[tid*256 + (n - 256)];
    else              v = att_W1[(256 + tid)*256 + (n - 512)];
    WpreT[n*256 + tid] = f2bf(v);
  } else if (b < 1024){
    int n = b - 768;
    W1T[n*512 + tid]       = f2bf(up_W1[tid*256 + n]);
    W1T[n*512 + 256 + tid] = f2bf(up_W1[(256 + tid)*256 + n]);
  } else {
    int n = b - 1024;
    W2T[n*256 + tid] = f2bf(up_W2[tid*256 + n]);
  }
}

// ---------------- K1: [Mf | P] = X @ [msg_W | W1a | W1b] ----------------
// 4 waves/block = 64 rows; all waves share one LDS-staged, XOR-swizzled B tile.
// tc (task @ W1d + att_b1) folded into P2 columns (nt >= 32).
__global__ __launch_bounds__(256) void k_gemm_pre(
    const float* __restrict__ X, const unsigned short* __restrict__ WpreT,
    const float* __restrict__ tabs,
    float* __restrict__ Mf, unsigned short* __restrict__ P)
{
  __shared__ __align__(16) unsigned short s_b[16*256]; // 8KB, swizzled elem ^= (n&7)<<3
  int tid = threadIdx.x, wv = tid >> 6, lane = tid & 63;
  int m0 = blockIdx.x*64 + wv*16;
  bool valid = (m0 < NN);
  int lo = lane & 15, hi = lane >> 4;
  bf16x8 a[8];
  if (valid){
    const float* xrow = X + (size_t)(m0 + lo)*256 + hi*8;
    #pragma unroll
    for (int kc = 0; kc < 8; ++kc){
      float4 f0 = *(const float4*)(xrow + kc*32);
      float4 f1 = *(const float4*)(xrow + kc*32 + 4);
      bf16x8 v;
      v[0]=(__bf16)f0.x; v[1]=(__bf16)f0.y; v[2]=(__bf16)f0.z; v[3]=(__bf16)f0.w;
      v[4]=(__bf16)f1.x; v[5]=(__bf16)f1.y; v[6]=(__bf16)f1.z; v[7]=(__bf16)f1.w;
      a[kc] = v;
    }
  }
  int sn = tid >> 4, sk0 = (tid & 15)*16;   // staging: thread -> (row n, 16 k-elems)
  int sswz = (sn & 7) << 3;
  int rswz = (lo & 7) << 3;
  for (int nt = 0; nt < 48; ++nt){
    __syncthreads();
    {
      const unsigned short* gsrc = WpreT + (size_t)(nt*16 + sn)*256 + sk0;
      uint4 d0 = *(const uint4*)(gsrc);
      uint4 d1 = *(const uint4*)(gsrc + 8);
      *(uint4*)(s_b + sn*256 + (sk0 ^ sswz))       = d0;
      *(uint4*)(s_b + sn*256 + ((sk0 + 8) ^ sswz)) = d1;
    }
    __syncthreads();
    if (!valid) continue;
    f32x4 acc = {0.f, 0.f, 0.f, 0.f};
    #pragma unroll
    for (int kc = 0; kc < 8; ++kc){
      bf16x8 bfrag = *(const bf16x8*)(s_b + lo*256 + ((kc*32 + hi*8) ^ rswz));
      acc = __builtin_amdgcn_mfma_f32_16x16x32_bf16(a[kc], bfrag, acc, 0, 0, 0);
    }
    int n0 = nt*16;
    if (nt < 16){
      float* mrow = Mf + (size_t)(m0 + hi*4)*256 + n0 + lo;
      #pragma unroll
      for (int r = 0; r < 4; ++r) mrow[(size_t)r*256] = acc[r];
    } else {
      float tcadd = (nt >= 32) ? tabs[TAB_TASKC + (n0 - 512 + lo)] : 0.f;
      unsigned short* prow = P + (size_t)(m0 + hi*4)*512 + (n0 - 256) + lo;
      #pragma unroll
      for (int r = 0; r < 4; ++r) prow[(size_t)r*512] = f2bf(acc[r] + tcadd);
    }
  }
}

// ---------------- K2a: in-degree histogram ----------------
__global__ __launch_bounds__(256) void k_hist(
    const int* __restrict__ eidx, int* __restrict__ cnt)
{
  int e = blockIdx.x*256 + threadIdx.x;
  if (e < NE) atomicAdd(&cnt[eidx[NE + e]], 1);
}

// ---------------- K2b: exclusive prefix sum (1 block, 20 elems/thread) ----------------
__global__ __launch_bounds__(1024) void k_scan(
    const int* __restrict__ cnt, int* __restrict__ ptrs, int* __restrict__ pwork)
{
  __shared__ int s[1024];
  int tid = threadIdx.x;
  int loc[20];          // exclusive prefix within this thread's 20 elems
  int tot = 0;
  #pragma unroll
  for (int j = 0; j < 20; ++j){
    int i = tid*20 + j;
    loc[j] = tot;
    tot += (i < NN) ? cnt[i] : 0;
  }
  s[tid] = tot;
  __syncthreads();
  #pragma unroll
  for (int off = 1; off < 1024; off <<= 1){
    int t = (tid >= off) ? s[tid - off] : 0;
    __syncthreads();
    s[tid] += t;
    __syncthreads();
  }
  int base = s[tid] - tot;   // exclusive prefix of thread totals
  #pragma unroll
  for (int j = 0; j < 20; ++j){
    int i = tid*20 + j;
    if (i < NN){
      ptrs[i]  = base + loc[j];
      pwork[i] = base + loc[j];
    }
  }
  if (tid == 1023) ptrs[NN] = s[1023];
}

// ---------------- K2c: CSR build (src|et packed, CSR slot via atomic) ----------------
__global__ __launch_bounds__(256) void k_csr_build(
    const int* __restrict__ eidx, const int* __restrict__ etype,
    int* __restrict__ pwork, unsigned int* __restrict__ srcet)
{
  int e = blockIdx.x*256 + threadIdx.x;
  if (e < NE){
    int dst = eidx[NE + e];
    int pos = atomicAdd(&pwork[dst], 1);
    srcet[pos] = (unsigned int)eidx[e] | ((unsigned int)etype[e] << 16);
  }
}

// ---------------- K3: per-node attention weights (1 wave/node, CSR order, no atomics) ----------------
__global__ __launch_bounds__(256) void k_att(
    const int* __restrict__ ptrs, const unsigned int* __restrict__ srcet,
    const unsigned short* __restrict__ P, const float* __restrict__ tabs,
    const float* __restrict__ attW2, const float* __restrict__ attb2,
    const float* __restrict__ escale, float* __restrict__ wbuf)
{
  int node = blockIdx.x*4 + (threadIdx.x >> 6);
  if (node >= NN) return;
  int lane = threadIdx.x & 63, c0 = lane*4;
  ushort4 p2v = *(const ushort4*)(P + (size_t)node*512 + 256 + c0);  // P2[dst] (+tc folded)
  float q0 = bf2f(p2v.x), q1 = bf2f(p2v.y), q2 = bf2f(p2v.z), q3 = bf2f(p2v.w);
  float4 w2 = *(const float4*)(attW2 + c0);
  float sc = escale[0], bb = attb2[0];
  int start = ptrs[node], end = ptrs[node + 1];
  for (int i = start; i < end; ++i){
    unsigned int se = srcet[i];
    int src = se & 0xFFFF, et = se >> 16;
    ushort4 p1 = *(const ushort4*)(P + (size_t)src*512 + c0);
    float4 ec = *(const float4*)(tabs + TAB_EC + et*256 + c0);
    float part = gelu_f(bf2f(p1.x) + q0 + ec.x)*w2.x
               + gelu_f(bf2f(p1.y) + q1 + ec.y)*w2.y
               + gelu_f(bf2f(p1.z) + q2 + ec.z)*w2.z
               + gelu_f(bf2f(p1.w) + q3 + ec.w)*w2.w;
    #pragma unroll
    for (int off = 32; off; off >>= 1) part += __shfl_xor(part, off);
    if (lane == 0) wbuf[i] = 1.0f + sc*tanhf(part + bb);
  }
}

// ---------------- K4: gather-aggregate + update MLP + residual + LayerNorm ----------------
// LDS: s_upd [16][512] u16 swizzled @0 ; s_y [16][260] f32 @0 (aliases s_upd, safe after GEMM1);
//      s_H [16][256] u16 swizzled @16640 ; mu/rs @24832. Total 24960 B -> ~5 blocks/CU.
__global__ __launch_bounds__(256) void k_final(
    const float* __restrict__ X, const int* __restrict__ ptrs,
    const unsigned int* __restrict__ srcet, const float* __restrict__ wbuf,
    const float* __restrict__ Mf, const float* __restrict__ tabs,
    const unsigned short* __restrict__ W1T, const unsigned short* __restrict__ W2T,
    const float* __restrict__ up_b1, const float* __restrict__ up_b2,
    const float* __restrict__ ln_g, const float* __restrict__ ln_b,
    float* __restrict__ out)
{
  __shared__ __align__(16) unsigned char smem[24960];
  unsigned short* s_upd = (unsigned short*)smem;        // bf16 [16][512], ^=(row&7)<<3
  float*          s_y   = (float*)smem;                 // f32 [16][260]  (aliases s_upd)
  unsigned short* s_H   = (unsigned short*)(smem + 16640); // bf16 [16][256], ^=(row&7)<<3
  float*          s_mu  = (float*)(smem + 24832);
  float*          s_rs  = (float*)(smem + 24896);
  int m0 = blockIdx.x*16;
  int tid = threadIdx.x;
  int wv = tid >> 6, lane = tid & 63;

  // stage X -> s_upd[:, 0:256] (bf16, swizzled)
  for (int i = tid; i < 16*256; i += 256){
    int rr = i >> 8, c = i & 255;
    s_upd[(rr << 9) | (c ^ ((rr & 7) << 3))] = f2bf(X[(size_t)(m0 + rr)*256 + c]);
  }
  __syncthreads();

  // gather-aggregate: wave wv handles rows 4wv..4wv+3; lane owns 4 dims
  {
    int c0 = lane*4;
    float4 ms = *(const float4*)(tabs + TAB_MSG_SCALE + c0);
    float4 mb = *(const float4*)(tabs + TAB_MSG_BETA  + c0);
    float4 us = *(const float4*)(tabs + TAB_UPD_SCALE + c0);
    float4 ub = *(const float4*)(tabs + TAB_UPD_BETA  + c0);
    for (int rr = 0; rr < 4; ++rr){
      int node = m0 + wv*4 + rr;
      int start = ptrs[node], end = ptrs[node + 1];
      float ax = 0.f, ay = 0.f, az = 0.f, aw = 0.f, W = 0.f;
      unsigned int se_n = 0; float w_n = 0.f;
      if (start < end){ se_n = srcet[start]; w_n = wbuf[start]; }
      for (int i = start; i < end; ++i){
        unsigned int se = se_n; float w = w_n;
        if (i + 1 < end){ se_n = srcet[i + 1]; w_n = wbuf[i + 1]; }
        int src = se & 0xFFFF, et = se >> 16;
        float4 mm = *(const float4*)(Mf + (size_t)src*256 + c0);
        float4 ev = *(const float4*)(tabs + TAB_EM + et*256 + c0);
        ax += w*(mm.x + ev.x);
        ay += w*(mm.y + ev.y);
        az += w*(mm.z + ev.z);
        aw += w*(mm.w + ev.w);
        W += w;
      }
      float d = fmaxf(W, 1.0f), rd = 1.0f / d;
      float vx = (ms.x*ax + mb.x*W)*rd*us.x + ub.x;
      float vy = (ms.y*ay + mb.y*W)*rd*us.y + ub.y;
      float vz = (ms.z*az + mb.z*W)*rd*us.z + ub.z;
      float vw = (ms.w*aw + mb.w*W)*rd*us.w + ub.w;
      int r = wv*4 + rr;
      int swz = (r & 7) << 3;
      ushort4 st = { f2bf(vx), f2bf(vy), f2bf(vz), f2bf(vw) };
      *(ushort4*)(s_upd + ((r << 9) | ((256 + c0) ^ swz))) = st;
    }
  }
  __syncthreads();

  int lo = lane & 15, hi = lane >> 4;
  // GEMM1: H = gelu(upd_in @ up_W1 + b1); wave wv covers cols [wv*64, wv*64+64)
  f32x4 acc[4];
  #pragma unroll
  for (int t = 0; t < 4; ++t){
    float b = up_b1[wv*64 + t*16 + lo];
    acc[t] = (f32x4){b, b, b, b};
  }
  #pragma unroll
  for (int kc = 0; kc < 16; ++kc){
    int ke = kc*32 + hi*8;
    bf16x8 af = *(const bf16x8*)(s_upd + ((lo << 9) | (ke ^ ((lo & 7) << 3))));
    #pragma unroll
    for (int t = 0; t < 4; ++t){
      int n = wv*64 + t*16 + lo;
      bf16x8 bf = *(const bf16x8*)(W1T + (size_t)n*512 + ke);
      acc[t] = __builtin_amdgcn_mfma_f32_16x16x32_bf16(af, bf, acc[t], 0, 0, 0);
    }
  }
  #pragma unroll
  for (int t = 0; t < 4; ++t){
    #pragma unroll
    for (int r = 0; r < 4; ++r){
      int row = hi*4 + r, n = wv*64 + t*16 + lo;
      s_H[(row << 8) | (n ^ ((row & 7) << 3))] = f2bf(gelu_f(acc[t][r]));
    }
  }
  __syncthreads();
  // GEMM2: updated = H @ up_W2 + b2  (s_y writes after this barrier -> s_upd dead)
  f32x4 acc2[4];
  #pragma unroll
  for (int t = 0; t < 4; ++t){
    float b = up_b2[wv*64 + t*16 + lo];
    acc2[t] = (f32x4){b, b, b, b};
  }
  #pragma unroll
  for (int kc = 0; kc < 8; ++kc){
    int ke = kc*32 + hi*8;
    bf16x8 af = *(const bf16x8*)(s_H + ((lo << 8) | (ke ^ ((lo & 7) << 3))));
    #pragma unroll
    for (int t = 0; t < 4; ++t){
      int n = wv*64 + t*16 + lo;
      bf16x8 bf = *(const bf16x8*)(W2T + (size_t)n*256 + ke);
      acc2[t] = __builtin_amdgcn_mfma_f32_16x16x32_bf16(af, bf, acc2[t], 0, 0, 0);
    }
  }
  #pragma unroll
  for (int t = 0; t < 4; ++t){
    #pragma unroll
    for (int r = 0; r < 4; ++r){
      int row = hi*4 + r, n = wv*64 + t*16 + lo;
      s_y[row*260 + n] = X[(size_t)(m0 + row)*256 + n] + acc2[t][r];
    }
  }
  __syncthreads();
  // LayerNorm
  {
    int r = tid >> 4, g = tid & 15;
    float sum = 0.f, sq = 0.f;
    for (int c = g; c < 256; c += 16){
      float v = s_y[r*260 + c];
      sum += v; sq += v*v;
    }
    #pragma unroll
    for (int off = 8; off; off >>= 1){
      sum += __shfl_xor(sum, off, 16);
      sq  += __shfl_xor(sq,  off, 16);
    }
    if (g == 0){
      float mu = sum * (1.0f/256.0f);
      float var = sq * (1.0f/256.0f) - mu*mu;
      s_mu[r] = mu;
      s_rs[r] = rsqrtf(var + 1e-5f);
    }
  }
  __syncthreads();
  for (int i = tid; i < 4096; i += 256){
    int rr = i >> 8, c = i & 255;
    out[(size_t)(m0 + rr)*256 + c] = (s_y[rr*260 + c] - s_mu[rr]) * s_rs[rr] * ln_g[c] + ln_b[c];
  }
}

extern "C" void kernel_launch(void* const* d_in, const int* in_sizes, int n_in,
                              void* d_out, int out_size, void* d_ws, size_t ws_size,
                              hipStream_t stream)
{
  (void)in_sizes; (void)n_in; (void)out_size;
  if (ws_size < WS_NEED) return;
  const float* X      = (const float*)d_in[0];
  const int*   eidx   = (const int*)d_in[1];
  const int*   etype  = (const int*)d_in[2];
  const float* task   = (const float*)d_in[3];
  const float* eemb   = (const float*)d_in[4];
  const float* msg_W  = (const float*)d_in[5];
  const float* msg_b  = (const float*)d_in[6];
  const float* att_W1 = (const float*)d_in[7];
  const float* att_b1 = (const float*)d_in[8];
  const float* att_W2 = (const float*)d_in[9];
  const float* att_b2 = (const float*)d_in[10];
  const float* escale = (const float*)d_in[11];
  const float* ma_W1  = (const float*)d_in[12];
  const float* ma_b1  = (const float*)d_in[13];
  const float* ma_W2  = (const float*)d_in[14];
  const float* ma_b2  = (const float*)d_in[15];
  const float* up_W1  = (const float*)d_in[16];
  const float* up_b1  = (const float*)d_in[17];
  const float* up_W2  = (const float*)d_in[18];
  const float* up_b2  = (const float*)d_in[19];
  const float* ua_W1  = (const float*)d_in[20];
  const float* ua_b1  = (const float*)d_in[21];
  const float* ua_W2  = (const float*)d_in[22];
  const float* ua_b2  = (const float*)d_in[23];
  const float* ln_g   = (const float*)d_in[24];
  const float* ln_b   = (const float*)d_in[25];
  char* ws = (char*)d_ws;
  float* tabs = (float*)ws;
  unsigned short* WpreT = (unsigned short*)(ws + OFF_WPRET);
  unsigned short* W1T   = (unsigned short*)(ws + OFF_W1T);
  unsigned short* W2T   = (unsigned short*)(ws + OFF_W2T);
  int*          cnt   = (int*)(ws + OFF_CNT);
  int*          ptrs  = (int*)(ws + OFF_PTRS);
  int*          pwork = (int*)(ws + OFF_PWORK);
  unsigned int* srcet = (unsigned int*)(ws + OFF_SRCET);
  float*        wbuf  = (float*)(ws + OFF_WE);
  float*        Mf    = (float*)(ws + OFF_MF);
  unsigned short* P   = (unsigned short*)(ws + OFF_P);
  float* out = (float*)d_out;

  hipMemsetAsync(cnt, 0, (size_t)NN*4, stream);
  k_tables<<<35, 256, 0, stream>>>(task, eemb, msg_W, msg_b, att_W1, att_b1,
                                   ma_W1, ma_b1, ma_W2, ma_b2,
                                   ua_W1, ua_b1, ua_W2, ua_b2, tabs);
  k_prep<<<1280, 256, 0, stream>>>(msg_W, att_W1, up_W1, up_W2, WpreT, W1T, W2T);
  k_gemm_pre<<<(NN + 63)/64, 256, 0, stream>>>(X, WpreT, tabs, Mf, P);
  k_hist<<<(NE + 255)/256, 256, 0, stream>>>(eidx, cnt);
  k_scan<<<1, 1024, 0, stream>>>(cnt, ptrs, pwork);
  k_csr_build<<<(NE + 255)/256, 256, 0, stream>>>(eidx, etype, pwork, srcet);
  k_att<<<(NN + 3)/4, 256, 0, stream>>>(ptrs, srcet, P, tabs, att_W2, att_b2,
                                        escale, wbuf);
  k_final<<<NN/16, 256, 0, stream>>>(X, ptrs, srcet, wbuf, Mf, tabs,
                                     W1T, W2T, up_b1, up_b2, ln_g, ln_b, out);
}

// Round 5
// 296.195 us; speedup vs baseline: 3.1122x; 1.0956x over previous
//
#include <hip/hip_runtime.h>
#include <hip/hip_bf16.h>

#define NN 20000
#define NE 200000

typedef __bf16 bf16x8 __attribute__((ext_vector_type(8)));
typedef float f32x4 __attribute__((ext_vector_type(4)));
typedef unsigned short u16x8 __attribute__((ext_vector_type(8)));

// ---- workspace layout (bytes) ----
constexpr int TAB_MSG_SCALE = 0;      // f32 element offsets within tabs
constexpr int TAB_MSG_BETA  = 256;
constexpr int TAB_UPD_SCALE = 512;
constexpr int TAB_UPD_BETA  = 768;
constexpr int TAB_TASKC     = 1024;   // task @ att_W1[768:1024] + att_b1
constexpr int TAB_EM        = 1280;   // 16*256  e@msg_W + msg_b
constexpr int TAB_EC        = 1280 + 4096; // 16*256  e@att_W1[512:768]
constexpr size_t OFF_WPRET = 40960;    // u16[768*256] n-major
constexpr size_t OFF_W1T   = 434176;   // u16[256*512]
constexpr size_t OFF_W2T   = 696320;   // u16[256*256]
constexpr size_t OFF_CNT   = 827392;   // i32[NN]
constexpr size_t OFF_PTRS  = 907392;   // i32[NN+1]
constexpr size_t OFF_PWORK = 987648;   // i32[NN]
constexpr size_t OFF_SRCET = 1067648;  // u32[NE]  src | et<<16 (CSR order)
constexpr size_t OFF_UPDB  = 1867648;  // u16[NN*256]  aggregated+modulated upd half (bf16)
constexpr size_t OFF_G     = 12107648; // u16[NN*512]  interleaved [P1|M] per 4-dim group
constexpr size_t OFF_P2B   = 32587648; // u16[NN*256]  P2 + taskc (bf16)
constexpr size_t WS_NEED   = 42827648;

__device__ __forceinline__ float bf2f(unsigned short u){
  union { unsigned int i; float f; } v; v.i = ((unsigned int)u) << 16; return v.f;
}
__device__ __forceinline__ unsigned short f2bf(float f){
  __bf16 h = (__bf16)f; unsigned short u; __builtin_memcpy(&u, &h, 2); return u;
}
__device__ __forceinline__ float gelu_f(float x){
  return 0.5f * x * (1.0f + erff(x * 0.70710678118654752f));
}

// ---------------- K0: tiny tables (proven) ----------------
__global__ __launch_bounds__(256) void k_tables(
    const float* __restrict__ task, const float* __restrict__ eemb,
    const float* __restrict__ msg_W, const float* __restrict__ msg_b,
    const float* __restrict__ att_W1, const float* __restrict__ att_b1,
    const float* __restrict__ ma_W1, const float* __restrict__ ma_b1,
    const float* __restrict__ ma_W2, const float* __restrict__ ma_b2,
    const float* __restrict__ ua_W1, const float* __restrict__ ua_b1,
    const float* __restrict__ ua_W2, const float* __restrict__ ua_b2,
    float* __restrict__ tabs)
{
  __shared__ float s_in[512];
  __shared__ float s_h[512];
  int b = blockIdx.x, tid = threadIdx.x;
  if (b < 2){
    const float* W1 = b ? ua_W1 : ma_W1;  const float* b1 = b ? ua_b1 : ma_b1;
    const float* W2 = b ? ua_W2 : ma_W2;  const float* b2 = b ? ua_b2 : ma_b2;
    s_in[tid] = task[tid];
    __syncthreads();
    #pragma unroll
    for (int jj = 0; jj < 2; ++jj){
      int j = tid + jj*256;
      float acc = b1[j];
      for (int k = 0; k < 256; ++k) acc += s_in[k] * W1[k*512 + j];
      s_h[j] = gelu_f(acc);
    }
    __syncthreads();
    float o[2];
    #pragma unroll
    for (int jj = 0; jj < 2; ++jj){
      int j = tid + jj*256;
      float acc = b2[j];
      for (int k = 0; k < 512; ++k) acc += s_h[k] * W2[k*512 + j];
      o[jj] = acc;
    }
    float* scale = tabs + (b ? TAB_UPD_SCALE : TAB_MSG_SCALE);
    float* beta  = tabs + (b ? TAB_UPD_BETA  : TAB_MSG_BETA);
    scale[tid] = 1.0f + 0.5f * tanhf(o[0]);
    beta[tid]  = o[1];
  } else if (b == 2){
    s_in[tid] = task[tid];
    __syncthreads();
    float acc = att_b1[tid];
    for (int k = 0; k < 256; ++k) acc += s_in[k] * att_W1[(768 + k)*256 + tid];
    tabs[TAB_TASKC + tid] = acc;
  } else if (b < 19){
    int t = b - 3;
    s_in[tid] = eemb[t*256 + tid];
    __syncthreads();
    float acc = msg_b[tid];
    for (int k = 0; k < 256; ++k) acc += s_in[k] * msg_W[k*256 + tid];
    tabs[TAB_EM + t*256 + tid] = acc;
  } else {
    int t = b - 19;
    s_in[tid] = eemb[t*256 + tid];
    __syncthreads();
    float acc = 0.f;
    for (int k = 0; k < 256; ++k) acc += s_in[k] * att_W1[(512 + k)*256 + tid];
    tabs[TAB_EC + t*256 + tid] = acc;
  }
}

// ---------------- K0b: bf16 transposed weight copies (proven) ----------------
__global__ __launch_bounds__(256) void k_prep(
    const float* __restrict__ msg_W, const float* __restrict__ att_W1,
    const float* __restrict__ up_W1, const float* __restrict__ up_W2,
    unsigned short* __restrict__ WpreT, unsigned short* __restrict__ W1T,
    unsigned short* __restrict__ W2T)
{
  int b = blockIdx.x, tid = threadIdx.x;
  if (b < 768){
    int n = b;
    float v;
    if (n < 256)      v = msg_W[tid*256 + n];
    else if (n < 512) v = att_W1[tid*256 + (n - 256)];
    else              v = att_W1[(256 + tid)*256 + (n - 512)];
    WpreT[n*256 + tid] = f2bf(v);
  } else if (b < 1024){
    int n = b - 768;
    W1T[n*512 + tid]       = f2bf(up_W1[tid*256 + n]);
    W1T[n*512 + 256 + tid] = f2bf(up_W1[(256 + tid)*256 + n]);
  } else {
    int n = b - 1024;
    W2T[n*256 + tid] = f2bf(up_W2[tid*256 + n]);
  }
}

// ---------------- K1: G=[P1|M interleaved], P2b = X @ [msg_W | W1a | W1b] ----------------
// 4 waves/block = 64 rows; LDS-staged XOR-swizzled B tile (proven round-4).
// Output mapping: WpreT cols 0..255 = msg_W (M), 256..511 = W1a (P1), 512..767 = W1b (P2).
// G row (512 u16): group d (0..63): elems [8d..8d+3]=P1[4d..4d+3], [8d+4..8d+7]=M[4d..4d+3].
__global__ __launch_bounds__(256) void k_gemm_pre(
    const float* __restrict__ X, const unsigned short* __restrict__ WpreT,
    const float* __restrict__ tabs,
    unsigned short* __restrict__ G, unsigned short* __restrict__ P2b)
{
  __shared__ __align__(16) unsigned short s_b[16*256]; // 8KB, swizzled elem ^= (n&7)<<3
  int tid = threadIdx.x, wv = tid >> 6, lane = tid & 63;
  int m0 = blockIdx.x*64 + wv*16;
  bool valid = (m0 < NN);
  int lo = lane & 15, hi = lane >> 4;
  bf16x8 a[8];
  if (valid){
    const float* xrow = X + (size_t)(m0 + lo)*256 + hi*8;
    #pragma unroll
    for (int kc = 0; kc < 8; ++kc){
      float4 f0 = *(const float4*)(xrow + kc*32);
      float4 f1 = *(const float4*)(xrow + kc*32 + 4);
      bf16x8 v;
      v[0]=(__bf16)f0.x; v[1]=(__bf16)f0.y; v[2]=(__bf16)f0.z; v[3]=(__bf16)f0.w;
      v[4]=(__bf16)f1.x; v[5]=(__bf16)f1.y; v[6]=(__bf16)f1.z; v[7]=(__bf16)f1.w;
      a[kc] = v;
    }
  }
  int sn = tid >> 4, sk0 = (tid & 15)*16;
  int sswz = (sn & 7) << 3;
  int rswz = (lo & 7) << 3;
  for (int nt = 0; nt < 48; ++nt){
    __syncthreads();
    {
      const unsigned short* gsrc = WpreT + (size_t)(nt*16 + sn)*256 + sk0;
      uint4 d0 = *(const uint4*)(gsrc);
      uint4 d1 = *(const uint4*)(gsrc + 8);
      *(uint4*)(s_b + sn*256 + (sk0 ^ sswz))       = d0;
      *(uint4*)(s_b + sn*256 + ((sk0 + 8) ^ sswz)) = d1;
    }
    __syncthreads();
    if (!valid) continue;
    f32x4 acc = {0.f, 0.f, 0.f, 0.f};
    #pragma unroll
    for (int kc = 0; kc < 8; ++kc){
      bf16x8 bfrag = *(const bf16x8*)(s_b + lo*256 + ((kc*32 + hi*8) ^ rswz));
      acc = __builtin_amdgcn_mfma_f32_16x16x32_bf16(a[kc], bfrag, acc, 0, 0, 0);
    }
    int n0 = nt*16;
    if (nt < 16){
      // M column j -> G elem (j>>2)*8 + 4 + (j&3)
      int j = n0 + lo;
      int elem = ((j >> 2) << 3) + 4 + (j & 3);
      unsigned short* grow = G + (size_t)(m0 + hi*4)*512 + elem;
      #pragma unroll
      for (int r = 0; r < 4; ++r) grow[(size_t)r*512] = f2bf(acc[r]);
    } else if (nt < 32){
      // P1 column j -> G elem (j>>2)*8 + (j&3)
      int j = n0 - 256 + lo;
      int elem = ((j >> 2) << 3) + (j & 3);
      unsigned short* grow = G + (size_t)(m0 + hi*4)*512 + elem;
      #pragma unroll
      for (int r = 0; r < 4; ++r) grow[(size_t)r*512] = f2bf(acc[r]);
    } else {
      int j = n0 - 512 + lo;
      float tcadd = tabs[TAB_TASKC + j];
      unsigned short* prow = P2b + (size_t)(m0 + hi*4)*256 + j;
      #pragma unroll
      for (int r = 0; r < 4; ++r) prow[(size_t)r*256] = f2bf(acc[r] + tcadd);
    }
  }
}

// ---------------- K2a: in-degree histogram ----------------
__global__ __launch_bounds__(256) void k_hist(
    const int* __restrict__ eidx, int* __restrict__ cnt)
{
  int e = blockIdx.x*256 + threadIdx.x;
  if (e < NE) atomicAdd(&cnt[eidx[NE + e]], 1);
}

// ---------------- K2b: exclusive prefix sum (1 block, 20 elems/thread) ----------------
__global__ __launch_bounds__(1024) void k_scan(
    const int* __restrict__ cnt, int* __restrict__ ptrs, int* __restrict__ pwork)
{
  __shared__ int s[1024];
  int tid = threadIdx.x;
  int loc[20];
  int tot = 0;
  #pragma unroll
  for (int j = 0; j < 20; ++j){
    int i = tid*20 + j;
    loc[j] = tot;
    tot += (i < NN) ? cnt[i] : 0;
  }
  s[tid] = tot;
  __syncthreads();
  #pragma unroll
  for (int off = 1; off < 1024; off <<= 1){
    int t = (tid >= off) ? s[tid - off] : 0;
    __syncthreads();
    s[tid] += t;
    __syncthreads();
  }
  int base = s[tid] - tot;
  #pragma unroll
  for (int j = 0; j < 20; ++j){
    int i = tid*20 + j;
    if (i < NN){
      ptrs[i]  = base + loc[j];
      pwork[i] = base + loc[j];
    }
  }
  if (tid == 1023) ptrs[NN] = s[1023];
}

// ---------------- K2c: CSR build ----------------
__global__ __launch_bounds__(256) void k_csr_build(
    const int* __restrict__ eidx, const int* __restrict__ etype,
    int* __restrict__ pwork, unsigned int* __restrict__ srcet)
{
  int e = blockIdx.x*256 + threadIdx.x;
  if (e < NE){
    int dst = eidx[NE + e];
    int pos = atomicAdd(&pwork[dst], 1);
    srcet[pos] = (unsigned int)eidx[e] | ((unsigned int)etype[e] << 16);
  }
}

// ---------------- K3: fused attention + aggregate (1 wave/node, 2-deep pipeline) ----------------
__global__ __launch_bounds__(256) void k_agg(
    const int* __restrict__ ptrs, const unsigned int* __restrict__ srcet,
    const unsigned short* __restrict__ G, const unsigned short* __restrict__ P2b,
    const float* __restrict__ tabs, const float* __restrict__ attW2,
    const float* __restrict__ attb2, const float* __restrict__ escale,
    unsigned short* __restrict__ updB)
{
  int node = blockIdx.x*4 + (threadIdx.x >> 6);
  if (node >= NN) return;
  int lane = threadIdx.x & 63, c0 = lane*4;
  ushort4 p2 = *(const ushort4*)(P2b + (size_t)node*256 + c0);
  float q0 = bf2f(p2.x), q1 = bf2f(p2.y), q2 = bf2f(p2.z), q3 = bf2f(p2.w);
  float4 w2 = *(const float4*)(attW2 + c0);
  float sc = escale[0], bb = attb2[0];
  float4 ms = *(const float4*)(tabs + TAB_MSG_SCALE + c0);
  float4 mb = *(const float4*)(tabs + TAB_MSG_BETA  + c0);
  float4 us = *(const float4*)(tabs + TAB_UPD_SCALE + c0);
  float4 ub = *(const float4*)(tabs + TAB_UPD_BETA  + c0);
  int start = ptrs[node], end = ptrs[node + 1];
  float ax = 0.f, ay = 0.f, az = 0.f, aw = 0.f, W = 0.f;
  unsigned int se0 = 0, se1 = 0;
  u16x8 g0 = {0,0,0,0,0,0,0,0};
  if (start < end){
    se0 = srcet[start];
    g0 = *(const u16x8*)(G + (size_t)(se0 & 0xFFFFu)*512 + lane*8);
    if (start + 1 < end) se1 = srcet[start + 1];
  }
  for (int i = start; i < end; ++i){
    u16x8 g1 = g0;
    unsigned int se2 = 0;
    if (i + 1 < end) g1 = *(const u16x8*)(G + (size_t)(se1 & 0xFFFFu)*512 + lane*8);
    if (i + 2 < end) se2 = srcet[i + 2];
    int et = (int)(se0 >> 16);
    float4 ec = *(const float4*)(tabs + TAB_EC + et*256 + c0);
    float part = gelu_f(bf2f(g0[0]) + q0 + ec.x)*w2.x
               + gelu_f(bf2f(g0[1]) + q1 + ec.y)*w2.y
               + gelu_f(bf2f(g0[2]) + q2 + ec.z)*w2.z
               + gelu_f(bf2f(g0[3]) + q3 + ec.w)*w2.w;
    #pragma unroll
    for (int off = 32; off; off >>= 1) part += __shfl_xor(part, off);
    float w = 1.0f + sc*tanhf(part + bb);
    float4 em = *(const float4*)(tabs + TAB_EM + et*256 + c0);
    ax += w*(bf2f(g0[4]) + em.x);
    ay += w*(bf2f(g0[5]) + em.y);
    az += w*(bf2f(g0[6]) + em.z);
    aw += w*(bf2f(g0[7]) + em.w);
    W += w;
    se0 = se1; se1 = se2; g0 = g1;
  }
  float d = fmaxf(W, 1.0f), rd = 1.0f / d;
  ushort4 st = { f2bf((ms.x*ax + mb.x*W)*rd*us.x + ub.x),
                 f2bf((ms.y*ay + mb.y*W)*rd*us.y + ub.y),
                 f2bf((ms.z*az + mb.z*W)*rd*us.z + ub.z),
                 f2bf((ms.w*aw + mb.w*W)*rd*us.w + ub.w) };
  *(ushort4*)(updB + (size_t)node*256 + c0) = st;
}

// ---------------- K4: dense update MLP + residual + LayerNorm ----------------
// A-frags straight from global (X f32 -> cvt, updB bf16). LDS: s_H 8K + s_y 16.6K.
__global__ __launch_bounds__(256) void k_mlp(
    const float* __restrict__ X, const unsigned short* __restrict__ updB,
    const unsigned short* __restrict__ W1T, const unsigned short* __restrict__ W2T,
    const float* __restrict__ up_b1, const float* __restrict__ up_b2,
    const float* __restrict__ ln_g, const float* __restrict__ ln_b,
    float* __restrict__ out)
{
  __shared__ __align__(16) unsigned char smem[24960];
  unsigned short* s_H  = (unsigned short*)smem;         // bf16 [16][256], ^=(row&7)<<3
  float*          s_y  = (float*)(smem + 8192);         // f32 [16][260]
  float*          s_mu = (float*)(smem + 24832);
  float*          s_rs = (float*)(smem + 24896);
  int m0 = blockIdx.x*16;
  int tid = threadIdx.x;
  int wv = tid >> 6, lane = tid & 63, lo = lane & 15, hi = lane >> 4;

  // A fragments: row m0+lo, k = kc*32 + hi*8; k<256 from X (cvt), k>=256 from updB
  bf16x8 a[16];
  {
    const float* xrow = X + (size_t)(m0 + lo)*256 + hi*8;
    #pragma unroll
    for (int kc = 0; kc < 8; ++kc){
      float4 f0 = *(const float4*)(xrow + kc*32);
      float4 f1 = *(const float4*)(xrow + kc*32 + 4);
      bf16x8 v;
      v[0]=(__bf16)f0.x; v[1]=(__bf16)f0.y; v[2]=(__bf16)f0.z; v[3]=(__bf16)f0.w;
      v[4]=(__bf16)f1.x; v[5]=(__bf16)f1.y; v[6]=(__bf16)f1.z; v[7]=(__bf16)f1.w;
      a[kc] = v;
    }
    const unsigned short* urow = updB + (size_t)(m0 + lo)*256 + hi*8;
    #pragma unroll
    for (int kc = 0; kc < 8; ++kc)
      a[8 + kc] = *(const bf16x8*)(urow + kc*32);
  }

  // GEMM1: H = gelu([X|upd] @ up_W1 + b1); wave wv covers cols [wv*64, wv*64+64)
  f32x4 acc[4];
  #pragma unroll
  for (int t = 0; t < 4; ++t){
    float b = up_b1[wv*64 + t*16 + lo];
    acc[t] = (f32x4){b, b, b, b};
  }
  #pragma unroll
  for (int kc = 0; kc < 16; ++kc){
    int ke = kc*32 + hi*8;
    #pragma unroll
    for (int t = 0; t < 4; ++t){
      int n = wv*64 + t*16 + lo;
      bf16x8 bf = *(const bf16x8*)(W1T + (size_t)n*512 + ke);
      acc[t] = __builtin_amdgcn_mfma_f32_16x16x32_bf16(a[kc], bf, acc[t], 0, 0, 0);
    }
  }
  #pragma unroll
  for (int t = 0; t < 4; ++t){
    #pragma unroll
    for (int r = 0; r < 4; ++r){
      int row = hi*4 + r, n = wv*64 + t*16 + lo;
      s_H[(row << 8) | (n ^ ((row & 7) << 3))] = f2bf(gelu_f(acc[t][r]));
    }
  }
  __syncthreads();
  // GEMM2: updated = H @ up_W2 + b2
  f32x4 acc2[4];
  #pragma unroll
  for (int t = 0; t < 4; ++t){
    float b = up_b2[wv*64 + t*16 + lo];
    acc2[t] = (f32x4){b, b, b, b};
  }
  #pragma unroll
  for (int kc = 0; kc < 8; ++kc){
    int ke = kc*32 + hi*8;
    bf16x8 af = *(const bf16x8*)(s_H + ((lo << 8) | (ke ^ ((lo & 7) << 3))));
    #pragma unroll
    for (int t = 0; t < 4; ++t){
      int n = wv*64 + t*16 + lo;
      bf16x8 bf = *(const bf16x8*)(W2T + (size_t)n*256 + ke);
      acc2[t] = __builtin_amdgcn_mfma_f32_16x16x32_bf16(af, bf, acc2[t], 0, 0, 0);
    }
  }
  #pragma unroll
  for (int t = 0; t < 4; ++t){
    #pragma unroll
    for (int r = 0; r < 4; ++r){
      int row = hi*4 + r, n = wv*64 + t*16 + lo;
      s_y[row*260 + n] = X[(size_t)(m0 + row)*256 + n] + acc2[t][r];
    }
  }
  __syncthreads();
  // LayerNorm
  {
    int r = tid >> 4, g = tid & 15;
    float sum = 0.f, sq = 0.f;
    for (int c = g; c < 256; c += 16){
      float v = s_y[r*260 + c];
      sum += v; sq += v*v;
    }
    #pragma unroll
    for (int off = 8; off; off >>= 1){
      sum += __shfl_xor(sum, off, 16);
      sq  += __shfl_xor(sq,  off, 16);
    }
    if (g == 0){
      float mu = sum * (1.0f/256.0f);
      float var = sq * (1.0f/256.0f) - mu*mu;
      s_mu[r] = mu;
      s_rs[r] = rsqrtf(var + 1e-5f);
    }
  }
  __syncthreads();
  for (int i = tid; i < 4096; i += 256){
    int rr = i >> 8, c = i & 255;
    out[(size_t)(m0 + rr)*256 + c] = (s_y[rr*260 + c] - s_mu[rr]) * s_rs[rr] * ln_g[c] + ln_b[c];
  }
}

extern "C" void kernel_launch(void* const* d_in, const int* in_sizes, int n_in,
                              void* d_out, int out_size, void* d_ws, size_t ws_size,
                              hipStream_t stream)
{
  (void)in_sizes; (void)n_in; (void)out_size;
  if (ws_size < WS_NEED) return;
  const float* X      = (const float*)d_in[0];
  const int*   eidx   = (const int*)d_in[1];
  const int*   etype  = (const int*)d_in[2];
  const float* task   = (const float*)d_in[3];
  const float* eemb   = (const float*)d_in[4];
  const float* msg_W  = (const float*)d_in[5];
  const float* msg_b  = (const float*)d_in[6];
  const float* att_W1 = (const float*)d_in[7];
  const float* att_b1 = (const float*)d_in[8];
  const float* att_W2 = (const float*)d_in[9];
  const float* att_b2 = (const float*)d_in[10];
  const float* escale = (const float*)d_in[11];
  const float* ma_W1  = (const float*)d_in[12];
  const float* ma_b1  = (const float*)d_in[13];
  const float* ma_W2  = (const float*)d_in[14];
  const float* ma_b2  = (const float*)d_in[15];
  const float* up_W1  = (const float*)d_in[16];
  const float* up_b1  = (const float*)d_in[17];
  const float* up_W2  = (const float*)d_in[18];
  const float* up_b2  = (const float*)d_in[19];
  const float* ua_W1  = (const float*)d_in[20];
  const float* ua_b1  = (const float*)d_in[21];
  const float* ua_W2  = (const float*)d_in[22];
  const float* ua_b2  = (const float*)d_in[23];
  const float* ln_g   = (const float*)d_in[24];
  const float* ln_b   = (const float*)d_in[25];
  char* ws = (char*)d_ws;
  float* tabs = (float*)ws;
  unsigned short* WpreT = (unsigned short*)(ws + OFF_WPRET);
  unsigned short* W1T   = (unsigned short*)(ws + OFF_W1T);
  unsigned short* W2T   = (unsigned short*)(ws + OFF_W2T);
  int*          cnt   = (int*)(ws + OFF_CNT);
  int*          ptrs  = (int*)(ws + OFF_PTRS);
  int*          pwork = (int*)(ws + OFF_PWORK);
  unsigned int* srcet = (unsigned int*)(ws + OFF_SRCET);
  unsigned short* updB = (unsigned short*)(ws + OFF_UPDB);
  unsigned short* G    = (unsigned short*)(ws + OFF_G);
  unsigned short* P2b  = (unsigned short*)(ws + OFF_P2B);
  float* out = (float*)d_out;

  hipMemsetAsync(cnt, 0, (size_t)NN*4, stream);
  k_tables<<<35, 256, 0, stream>>>(task, eemb, msg_W, msg_b, att_W1, att_b1,
                                   ma_W1, ma_b1, ma_W2, ma_b2,
                                   ua_W1, ua_b1, ua_W2, ua_b2, tabs);
  k_prep<<<1280, 256, 0, stream>>>(msg_W, att_W1, up_W1, up_W2, WpreT, W1T, W2T);
  k_gemm_pre<<<(NN + 63)/64, 256, 0, stream>>>(X, WpreT, tabs, G, P2b);
  k_hist<<<(NE + 255)/256, 256, 0, stream>>>(eidx, cnt);
  k_scan<<<1, 1024, 0, stream>>>(cnt, ptrs, pwork);
  k_csr_build<<<(NE + 255)/256, 256, 0, stream>>>(eidx, etype, pwork, srcet);
  k_agg<<<(NN + 3)/4, 256, 0, stream>>>(ptrs, srcet, G, P2b, tabs,
                                        att_W2, att_b2, escale, updB);
  k_mlp<<<NN/16, 256, 0, stream>>>(X, updB, W1T, W2T, up_b1, up_b2,
                                   ln_g, ln_b, out);
}

// Round 6
// 282.646 us; speedup vs baseline: 3.2614x; 1.0479x over previous
//
#include <hip/hip_runtime.h>
#include <hip/hip_bf16.h>

#define NN 20000
#define NE 200000

typedef __bf16 bf16x8 __attribute__((ext_vector_type(8)));
typedef float f32x4 __attribute__((ext_vector_type(4)));
typedef unsigned short u16x8 __attribute__((ext_vector_type(8)));

// ---- workspace layout (bytes) ----
constexpr int TAB_MSG_SCALE = 0;      // f32 element offsets within tabs
constexpr int TAB_MSG_BETA  = 256;
constexpr int TAB_UPD_SCALE = 512;
constexpr int TAB_UPD_BETA  = 768;
constexpr int TAB_TASKC     = 1024;   // task @ att_W1[768:1024] + att_b1
constexpr int TAB_EM        = 1280;   // 16*256  e@msg_W + msg_b
constexpr int TAB_EC        = 1280 + 4096; // 16*256  e@att_W1[512:768]
constexpr size_t OFF_WPRET = 40960;    // u16[768*256] n-major
constexpr size_t OFF_W1T   = 434176;   // u16[256*512]
constexpr size_t OFF_W2T   = 696320;   // u16[256*256]
constexpr size_t OFF_CNT   = 827392;   // i32[NN]
constexpr size_t OFF_PTRS  = 907392;   // i32[NN+1]
constexpr size_t OFF_PWORK = 987648;   // i32[NN]
constexpr size_t OFF_SRCET = 1067648;  // u32[NE]  src | et<<16 (CSR order)
constexpr size_t OFF_UPDB  = 1867648;  // u16[NN*256]  aggregated+modulated upd half (bf16)
constexpr size_t OFF_G     = 12107648; // u16[NN*512]  interleaved [P1|M] per 4-dim group
constexpr size_t OFF_P2B   = 32587648; // u16[NN*256]  P2 + taskc (bf16)
constexpr size_t WS_NEED   = 42827648;

__device__ __forceinline__ float bf2f(unsigned short u){
  union { unsigned int i; float f; } v; v.i = ((unsigned int)u) << 16; return v.f;
}
__device__ __forceinline__ unsigned short f2bf(float f){
  __bf16 h = (__bf16)f; unsigned short u; __builtin_memcpy(&u, &h, 2); return u;
}
__device__ __forceinline__ float gelu_f(float x){
  return 0.5f * x * (1.0f + erff(x * 0.70710678118654752f));
}
// fast sigmoid-gelu (attention path only): max abs err ~0.01 vs exact
__device__ __forceinline__ float gelu_fast(float x){
  return x / (1.0f + __expf(-1.702f * x));
}
// overflow-safe fast tanh: 1 - 2/(e^{2x}+1); exact limits at +/-inf
__device__ __forceinline__ float tanh_fast(float x){
  float e = __expf(2.0f * x);
  return 1.0f - 2.0f / (e + 1.0f);
}

// ---------------- K0: tiny tables (proven) ----------------
__global__ __launch_bounds__(256) void k_tables(
    const float* __restrict__ task, const float* __restrict__ eemb,
    const float* __restrict__ msg_W, const float* __restrict__ msg_b,
    const float* __restrict__ att_W1, const float* __restrict__ att_b1,
    const float* __restrict__ ma_W1, const float* __restrict__ ma_b1,
    const float* __restrict__ ma_W2, const float* __restrict__ ma_b2,
    const float* __restrict__ ua_W1, const float* __restrict__ ua_b1,
    const float* __restrict__ ua_W2, const float* __restrict__ ua_b2,
    float* __restrict__ tabs)
{
  __shared__ float s_in[512];
  __shared__ float s_h[512];
  int b = blockIdx.x, tid = threadIdx.x;
  if (b < 2){
    const float* W1 = b ? ua_W1 : ma_W1;  const float* b1 = b ? ua_b1 : ma_b1;
    const float* W2 = b ? ua_W2 : ma_W2;  const float* b2 = b ? ua_b2 : ma_b2;
    s_in[tid] = task[tid];
    __syncthreads();
    #pragma unroll
    for (int jj = 0; jj < 2; ++jj){
      int j = tid + jj*256;
      float acc = b1[j];
      for (int k = 0; k < 256; ++k) acc += s_in[k] * W1[k*512 + j];
      s_h[j] = gelu_f(acc);
    }
    __syncthreads();
    float o[2];
    #pragma unroll
    for (int jj = 0; jj < 2; ++jj){
      int j = tid + jj*256;
      float acc = b2[j];
      for (int k = 0; k < 512; ++k) acc += s_h[k] * W2[k*512 + j];
      o[jj] = acc;
    }
    float* scale = tabs + (b ? TAB_UPD_SCALE : TAB_MSG_SCALE);
    float* beta  = tabs + (b ? TAB_UPD_BETA  : TAB_MSG_BETA);
    scale[tid] = 1.0f + 0.5f * tanhf(o[0]);
    beta[tid]  = o[1];
  } else if (b == 2){
    s_in[tid] = task[tid];
    __syncthreads();
    float acc = att_b1[tid];
    for (int k = 0; k < 256; ++k) acc += s_in[k] * att_W1[(768 + k)*256 + tid];
    tabs[TAB_TASKC + tid] = acc;
  } else if (b < 19){
    int t = b - 3;
    s_in[tid] = eemb[t*256 + tid];
    __syncthreads();
    float acc = msg_b[tid];
    for (int k = 0; k < 256; ++k) acc += s_in[k] * msg_W[k*256 + tid];
    tabs[TAB_EM + t*256 + tid] = acc;
  } else {
    int t = b - 19;
    s_in[tid] = eemb[t*256 + tid];
    __syncthreads();
    float acc = 0.f;
    for (int k = 0; k < 256; ++k) acc += s_in[k] * att_W1[(512 + k)*256 + tid];
    tabs[TAB_EC + t*256 + tid] = acc;
  }
}

// ---------------- K0b: bf16 transposed weight copies (proven) ----------------
__global__ __launch_bounds__(256) void k_prep(
    const float* __restrict__ msg_W, const float* __restrict__ att_W1,
    const float* __restrict__ up_W1, const float* __restrict__ up_W2,
    unsigned short* __restrict__ WpreT, unsigned short* __restrict__ W1T,
    unsigned short* __restrict__ W2T)
{
  int b = blockIdx.x, tid = threadIdx.x;
  if (b < 768){
    int n = b;
    float v;
    if (n < 256)      v = msg_W[tid*256 + n];
    else if (n < 512) v = att_W1[tid*256 + (n - 256)];
    else              v = att_W1[(256 + tid)*256 + (n - 512)];
    WpreT[n*256 + tid] = f2bf(v);
  } else if (b < 1024){
    int n = b - 768;
    W1T[n*512 + tid]       = f2bf(up_W1[tid*256 + n]);
    W1T[n*512 + 256 + tid] = f2bf(up_W1[(256 + tid)*256 + n]);
  } else {
    int n = b - 1024;
    W2T[n*256 + tid] = f2bf(up_W2[tid*256 + n]);
  }
}

// ---------------- K1: G=[P1|M interleaved], P2b = X @ [msg_W | W1a | W1b] (proven) ----------------
__global__ __launch_bounds__(256) void k_gemm_pre(
    const float* __restrict__ X, const unsigned short* __restrict__ WpreT,
    const float* __restrict__ tabs,
    unsigned short* __restrict__ G, unsigned short* __restrict__ P2b)
{
  __shared__ __align__(16) unsigned short s_b[16*256]; // 8KB, swizzled elem ^= (n&7)<<3
  int tid = threadIdx.x, wv = tid >> 6, lane = tid & 63;
  int m0 = blockIdx.x*64 + wv*16;
  bool valid = (m0 < NN);
  int lo = lane & 15, hi = lane >> 4;
  bf16x8 a[8];
  if (valid){
    const float* xrow = X + (size_t)(m0 + lo)*256 + hi*8;
    #pragma unroll
    for (int kc = 0; kc < 8; ++kc){
      float4 f0 = *(const float4*)(xrow + kc*32);
      float4 f1 = *(const float4*)(xrow + kc*32 + 4);
      bf16x8 v;
      v[0]=(__bf16)f0.x; v[1]=(__bf16)f0.y; v[2]=(__bf16)f0.z; v[3]=(__bf16)f0.w;
      v[4]=(__bf16)f1.x; v[5]=(__bf16)f1.y; v[6]=(__bf16)f1.z; v[7]=(__bf16)f1.w;
      a[kc] = v;
    }
  }
  int sn = tid >> 4, sk0 = (tid & 15)*16;
  int sswz = (sn & 7) << 3;
  int rswz = (lo & 7) << 3;
  for (int nt = 0; nt < 48; ++nt){
    __syncthreads();
    {
      const unsigned short* gsrc = WpreT + (size_t)(nt*16 + sn)*256 + sk0;
      uint4 d0 = *(const uint4*)(gsrc);
      uint4 d1 = *(const uint4*)(gsrc + 8);
      *(uint4*)(s_b + sn*256 + (sk0 ^ sswz))       = d0;
      *(uint4*)(s_b + sn*256 + ((sk0 + 8) ^ sswz)) = d1;
    }
    __syncthreads();
    if (!valid) continue;
    f32x4 acc = {0.f, 0.f, 0.f, 0.f};
    #pragma unroll
    for (int kc = 0; kc < 8; ++kc){
      bf16x8 bfrag = *(const bf16x8*)(s_b + lo*256 + ((kc*32 + hi*8) ^ rswz));
      acc = __builtin_amdgcn_mfma_f32_16x16x32_bf16(a[kc], bfrag, acc, 0, 0, 0);
    }
    int n0 = nt*16;
    if (nt < 16){
      int j = n0 + lo;
      int elem = ((j >> 2) << 3) + 4 + (j & 3);
      unsigned short* grow = G + (size_t)(m0 + hi*4)*512 + elem;
      #pragma unroll
      for (int r = 0; r < 4; ++r) grow[(size_t)r*512] = f2bf(acc[r]);
    } else if (nt < 32){
      int j = n0 - 256 + lo;
      int elem = ((j >> 2) << 3) + (j & 3);
      unsigned short* grow = G + (size_t)(m0 + hi*4)*512 + elem;
      #pragma unroll
      for (int r = 0; r < 4; ++r) grow[(size_t)r*512] = f2bf(acc[r]);
    } else {
      int j = n0 - 512 + lo;
      float tcadd = tabs[TAB_TASKC + j];
      unsigned short* prow = P2b + (size_t)(m0 + hi*4)*256 + j;
      #pragma unroll
      for (int r = 0; r < 4; ++r) prow[(size_t)r*256] = f2bf(acc[r] + tcadd);
    }
  }
}

// ---------------- K2a: in-degree histogram ----------------
__global__ __launch_bounds__(256) void k_hist(
    const int* __restrict__ eidx, int* __restrict__ cnt)
{
  int e = blockIdx.x*256 + threadIdx.x;
  if (e < NE) atomicAdd(&cnt[eidx[NE + e]], 1);
}

// ---------------- K2b: exclusive prefix sum (1 block, 20 elems/thread) ----------------
__global__ __launch_bounds__(1024) void k_scan(
    const int* __restrict__ cnt, int* __restrict__ ptrs, int* __restrict__ pwork)
{
  __shared__ int s[1024];
  int tid = threadIdx.x;
  int loc[20];
  int tot = 0;
  #pragma unroll
  for (int j = 0; j < 20; ++j){
    int i = tid*20 + j;
    loc[j] = tot;
    tot += (i < NN) ? cnt[i] : 0;
  }
  s[tid] = tot;
  __syncthreads();
  #pragma unroll
  for (int off = 1; off < 1024; off <<= 1){
    int t = (tid >= off) ? s[tid - off] : 0;
    __syncthreads();
    s[tid] += t;
    __syncthreads();
  }
  int base = s[tid] - tot;
  #pragma unroll
  for (int j = 0; j < 20; ++j){
    int i = tid*20 + j;
    if (i < NN){
      ptrs[i]  = base + loc[j];
      pwork[i] = base + loc[j];
    }
  }
  if (tid == 1023) ptrs[NN] = s[1023];
}

// ---------------- K2c: CSR build ----------------
__global__ __launch_bounds__(256) void k_csr_build(
    const int* __restrict__ eidx, const int* __restrict__ etype,
    int* __restrict__ pwork, unsigned int* __restrict__ srcet)
{
  int e = blockIdx.x*256 + threadIdx.x;
  if (e < NE){
    int dst = eidx[NE + e];
    int pos = atomicAdd(&pwork[dst], 1);
    srcet[pos] = (unsigned int)eidx[e] | ((unsigned int)etype[e] << 16);
  }
}

// ---------------- K3: fused attention + aggregate (1 wave/node, fast transcendentals) ----------------
__global__ __launch_bounds__(256) void k_agg(
    const int* __restrict__ ptrs, const unsigned int* __restrict__ srcet,
    const unsigned short* __restrict__ G, const unsigned short* __restrict__ P2b,
    const float* __restrict__ tabs, const float* __restrict__ attW2,
    const float* __restrict__ attb2, const float* __restrict__ escale,
    unsigned short* __restrict__ updB)
{
  int node = blockIdx.x*4 + (threadIdx.x >> 6);
  if (node >= NN) return;
  int lane = threadIdx.x & 63, c0 = lane*4;
  ushort4 p2 = *(const ushort4*)(P2b + (size_t)node*256 + c0);
  float q0 = bf2f(p2.x), q1 = bf2f(p2.y), q2 = bf2f(p2.z), q3 = bf2f(p2.w);
  float4 w2 = *(const float4*)(attW2 + c0);
  float sc = escale[0], bb = attb2[0];
  float4 ms = *(const float4*)(tabs + TAB_MSG_SCALE + c0);
  float4 mb = *(const float4*)(tabs + TAB_MSG_BETA  + c0);
  float4 us = *(const float4*)(tabs + TAB_UPD_SCALE + c0);
  float4 ub = *(const float4*)(tabs + TAB_UPD_BETA  + c0);
  int start = ptrs[node], end = ptrs[node + 1];
  float ax = 0.f, ay = 0.f, az = 0.f, aw = 0.f, W = 0.f;
  unsigned int se0 = 0, se1 = 0;
  u16x8 g0 = {0,0,0,0,0,0,0,0};
  if (start < end){
    se0 = srcet[start];
    g0 = *(const u16x8*)(G + (size_t)(se0 & 0xFFFFu)*512 + lane*8);
    if (start + 1 < end) se1 = srcet[start + 1];
  }
  for (int i = start; i < end; ++i){
    u16x8 g1 = g0;
    unsigned int se2 = 0;
    if (i + 1 < end) g1 = *(const u16x8*)(G + (size_t)(se1 & 0xFFFFu)*512 + lane*8);
    if (i + 2 < end) se2 = srcet[i + 2];
    int et = (int)(se0 >> 16);
    float4 ec = *(const float4*)(tabs + TAB_EC + et*256 + c0);
    float part = gelu_fast(bf2f(g0[0]) + q0 + ec.x)*w2.x
               + gelu_fast(bf2f(g0[1]) + q1 + ec.y)*w2.y
               + gelu_fast(bf2f(g0[2]) + q2 + ec.z)*w2.z
               + gelu_fast(bf2f(g0[3]) + q3 + ec.w)*w2.w;
    #pragma unroll
    for (int off = 32; off; off >>= 1) part += __shfl_xor(part, off);
    float w = 1.0f + sc*tanh_fast(part + bb);
    float4 em = *(const float4*)(tabs + TAB_EM + et*256 + c0);
    ax += w*(bf2f(g0[4]) + em.x);
    ay += w*(bf2f(g0[5]) + em.y);
    az += w*(bf2f(g0[6]) + em.z);
    aw += w*(bf2f(g0[7]) + em.w);
    W += w;
    se0 = se1; se1 = se2; g0 = g1;
  }
  float d = fmaxf(W, 1.0f), rd = 1.0f / d;
  ushort4 st = { f2bf((ms.x*ax + mb.x*W)*rd*us.x + ub.x),
                 f2bf((ms.y*ay + mb.y*W)*rd*us.y + ub.y),
                 f2bf((ms.z*az + mb.z*W)*rd*us.z + ub.z),
                 f2bf((ms.w*aw + mb.w*W)*rd*us.w + ub.w) };
  *(ushort4*)(updB + (size_t)node*256 + c0) = st;
}

// ---------------- K4: dense update MLP + residual + LayerNorm (proven) ----------------
__global__ __launch_bounds__(256) void k_mlp(
    const float* __restrict__ X, const unsigned short* __restrict__ updB,
    const unsigned short* __restrict__ W1T, const unsigned short* __restrict__ W2T,
    const float* __restrict__ up_b1, const float* __restrict__ up_b2,
    const float* __restrict__ ln_g, const float* __restrict__ ln_b,
    float* __restrict__ out)
{
  __shared__ __align__(16) unsigned char smem[24960];
  unsigned short* s_H  = (unsigned short*)smem;         // bf16 [16][256], ^=(row&7)<<3
  float*          s_y  = (float*)(smem + 8192);         // f32 [16][260]
  float*          s_mu = (float*)(smem + 24832);
  float*          s_rs = (float*)(smem + 24896);
  int m0 = blockIdx.x*16;
  int tid = threadIdx.x;
  int wv = tid >> 6, lane = tid & 63, lo = lane & 15, hi = lane >> 4;

  bf16x8 a[16];
  {
    const float* xrow = X + (size_t)(m0 + lo)*256 + hi*8;
    #pragma unroll
    for (int kc = 0; kc < 8; ++kc){
      float4 f0 = *(const float4*)(xrow + kc*32);
      float4 f1 = *(const float4*)(xrow + kc*32 + 4);
      bf16x8 v;
      v[0]=(__bf16)f0.x; v[1]=(__bf16)f0.y; v[2]=(__bf16)f0.z; v[3]=(__bf16)f0.w;
      v[4]=(__bf16)f1.x; v[5]=(__bf16)f1.y; v[6]=(__bf16)f1.z; v[7]=(__bf16)f1.w;
      a[kc] = v;
    }
    const unsigned short* urow = updB + (size_t)(m0 + lo)*256 + hi*8;
    #pragma unroll
    for (int kc = 0; kc < 8; ++kc)
      a[8 + kc] = *(const bf16x8*)(urow + kc*32);
  }

  f32x4 acc[4];
  #pragma unroll
  for (int t = 0; t < 4; ++t){
    float b = up_b1[wv*64 + t*16 + lo];
    acc[t] = (f32x4){b, b, b, b};
  }
  #pragma unroll
  for (int kc = 0; kc < 16; ++kc){
    int ke = kc*32 + hi*8;
    #pragma unroll
    for (int t = 0; t < 4; ++t){
      int n = wv*64 + t*16 + lo;
      bf16x8 bf = *(const bf16x8*)(W1T + (size_t)n*512 + ke);
      acc[t] = __builtin_amdgcn_mfma_f32_16x16x32_bf16(a[kc], bf, acc[t], 0, 0, 0);
    }
  }
  #pragma unroll
  for (int t = 0; t < 4; ++t){
    #pragma unroll
    for (int r = 0; r < 4; ++r){
      int row = hi*4 + r, n = wv*64 + t*16 + lo;
      s_H[(row << 8) | (n ^ ((row & 7) << 3))] = f2bf(gelu_f(acc[t][r]));
    }
  }
  __syncthreads();
  f32x4 acc2[4];
  #pragma unroll
  for (int t = 0; t < 4; ++t){
    float b = up_b2[wv*64 + t*16 + lo];
    acc2[t] = (f32x4){b, b, b, b};
  }
  #pragma unroll
  for (int kc = 0; kc < 8; ++kc){
    int ke = kc*32 + hi*8;
    bf16x8 af = *(const bf16x8*)(s_H + ((lo << 8) | (ke ^ ((lo & 7) << 3))));
    #pragma unroll
    for (int t = 0; t < 4; ++t){
      int n = wv*64 + t*16 + lo;
      bf16x8 bf = *(const bf16x8*)(W2T + (size_t)n*256 + ke);
      acc2[t] = __builtin_amdgcn_mfma_f32_16x16x32_bf16(af, bf, acc2[t], 0, 0, 0);
    }
  }
  #pragma unroll
  for (int t = 0; t < 4; ++t){
    #pragma unroll
    for (int r = 0; r < 4; ++r){
      int row = hi*4 + r, n = wv*64 + t*16 + lo;
      s_y[row*260 + n] = X[(size_t)(m0 + row)*256 + n] + acc2[t][r];
    }
  }
  __syncthreads();
  {
    int r = tid >> 4, g = tid & 15;
    float sum = 0.f, sq = 0.f;
    for (int c = g; c < 256; c += 16){
      float v = s_y[r*260 + c];
      sum += v; sq += v*v;
    }
    #pragma unroll
    for (int off = 8; off; off >>= 1){
      sum += __shfl_xor(sum, off, 16);
      sq  += __shfl_xor(sq,  off, 16);
    }
    if (g == 0){
      float mu = sum * (1.0f/256.0f);
      float var = sq * (1.0f/256.0f) - mu*mu;
      s_mu[r] = mu;
      s_rs[r] = rsqrtf(var + 1e-5f);
    }
  }
  __syncthreads();
  for (int i = tid; i < 4096; i += 256){
    int rr = i >> 8, c = i & 255;
    out[(size_t)(m0 + rr)*256 + c] = (s_y[rr*260 + c] - s_mu[rr]) * s_rs[rr] * ln_g[c] + ln_b[c];
  }
}

extern "C" void kernel_launch(void* const* d_in, const int* in_sizes, int n_in,
                              void* d_out, int out_size, void* d_ws, size_t ws_size,
                              hipStream_t stream)
{
  (void)in_sizes; (void)n_in; (void)out_size;
  if (ws_size < WS_NEED) return;
  const float* X      = (const float*)d_in[0];
  const int*   eidx   = (const int*)d_in[1];
  const int*   etype  = (const int*)d_in[2];
  const float* task   = (const float*)d_in[3];
  const float* eemb   = (const float*)d_in[4];
  const float* msg_W  = (const float*)d_in[5];
  const float* msg_b  = (const float*)d_in[6];
  const float* att_W1 = (const float*)d_in[7];
  const float* att_b1 = (const float*)d_in[8];
  const float* att_W2 = (const float*)d_in[9];
  const float* att_b2 = (const float*)d_in[10];
  const float* escale = (const float*)d_in[11];
  const float* ma_W1  = (const float*)d_in[12];
  const float* ma_b1  = (const float*)d_in[13];
  const float* ma_W2  = (const float*)d_in[14];
  const float* ma_b2  = (const float*)d_in[15];
  const float* up_W1  = (const float*)d_in[16];
  const float* up_b1  = (const float*)d_in[17];
  const float* up_W2  = (const float*)d_in[18];
  const float* up_b2  = (const float*)d_in[19];
  const float* ua_W1  = (const float*)d_in[20];
  const float* ua_b1  = (const float*)d_in[21];
  const float* ua_W2  = (const float*)d_in[22];
  const float* ua_b2  = (const float*)d_in[23];
  const float* ln_g   = (const float*)d_in[24];
  const float* ln_b   = (const float*)d_in[25];
  char* ws = (char*)d_ws;
  float* tabs = (float*)ws;
  unsigned short* WpreT = (unsigned short*)(ws + OFF_WPRET);
  unsigned short* W1T   = (unsigned short*)(ws + OFF_W1T);
  unsigned short* W2T   = (unsigned short*)(ws + OFF_W2T);
  int*          cnt   = (int*)(ws + OFF_CNT);
  int*          ptrs  = (int*)(ws + OFF_PTRS);
  int*          pwork = (int*)(ws + OFF_PWORK);
  unsigned int* srcet = (unsigned int*)(ws + OFF_SRCET);
  unsigned short* updB = (unsigned short*)(ws + OFF_UPDB);
  unsigned short* G    = (unsigned short*)(ws + OFF_G);
  unsigned short* P2b  = (unsigned short*)(ws + OFF_P2B);
  float* out = (float*)d_out;

  hipMemsetAsync(cnt, 0, (size_t)NN*4, stream);
  k_tables<<<35, 256, 0, stream>>>(task, eemb, msg_W, msg_b, att_W1, att_b1,
                                   ma_W1, ma_b1, ma_W2, ma_b2,
                                   ua_W1, ua_b1, ua_W2, ua_b2, tabs);
  k_prep<<<1280, 256, 0, stream>>>(msg_W, att_W1, up_W1, up_W2, WpreT, W1T, W2T);
  k_gemm_pre<<<(NN + 63)/64, 256, 0, stream>>>(X, WpreT, tabs, G, P2b);
  k_hist<<<(NE + 255)/256, 256, 0, stream>>>(eidx, cnt);
  k_scan<<<1, 1024, 0, stream>>>(cnt, ptrs, pwork);
  k_csr_build<<<(NE + 255)/256, 256, 0, stream>>>(eidx, etype, pwork, srcet);
  k_agg<<<(NN + 3)/4, 256, 0, stream>>>(ptrs, srcet, G, P2b, tabs,
                                        att_W2, att_b2, escale, updB);
  k_mlp<<<NN/16, 256, 0, stream>>>(X, updB, W1T, W2T, up_b1, up_b2,
                                   ln_g, ln_b, out);
}

// Round 7
// 262.304 us; speedup vs baseline: 3.5143x; 1.0776x over previous
//
#include <hip/hip_runtime.h>
#include <hip/hip_bf16.h>

#define NN 20000
#define NE 200000

typedef __bf16 bf16x8 __attribute__((ext_vector_type(8)));
typedef float f32x4 __attribute__((ext_vector_type(4)));
typedef unsigned short u16x8 __attribute__((ext_vector_type(8)));

// ---- workspace layout (bytes) ----
constexpr int TAB_MSG_SCALE = 0;      // f32 element offsets within tabs
constexpr int TAB_MSG_BETA  = 256;
constexpr int TAB_UPD_SCALE = 512;
constexpr int TAB_UPD_BETA  = 768;
constexpr int TAB_TASKC     = 1024;   // task @ att_W1[768:1024] + att_b1
constexpr int TAB_EM        = 1280;   // 16*256  e@msg_W + msg_b
constexpr int TAB_EC        = 1280 + 4096; // 16*256  e@att_W1[512:768]
constexpr size_t OFF_WPRET = 40960;    // u16[768*256] n-major
constexpr size_t OFF_W1T   = 434176;   // u16[256*512]
constexpr size_t OFF_W2T   = 696320;   // u16[256*256]
constexpr size_t OFF_CNT   = 827392;   // i32[NN]
constexpr size_t OFF_PTRS  = 907392;   // i32[NN+1]
constexpr size_t OFF_PWORK = 987648;   // i32[NN]
constexpr size_t OFF_SRCET = 1067648;  // u32[NE]  src | et<<16 (CSR order)
constexpr size_t OFF_UPDB  = 1867648;  // u16[NN*256]  aggregated+modulated upd half (bf16)
constexpr size_t OFF_G     = 12107648; // u16[NN*512]  interleaved [P1|M] per 4-dim group
constexpr size_t OFF_P2B   = 32587648; // u16[NN*256]  P2 + taskc (bf16)
constexpr size_t WS_NEED   = 42827648;

__device__ __forceinline__ float bf2f(unsigned short u){
  union { unsigned int i; float f; } v; v.i = ((unsigned int)u) << 16; return v.f;
}
__device__ __forceinline__ unsigned short f2bf(float f){
  __bf16 h = (__bf16)f; unsigned short u; __builtin_memcpy(&u, &h, 2); return u;
}
__device__ __forceinline__ float gelu_f(float x){
  return 0.5f * x * (1.0f + erff(x * 0.70710678118654752f));
}
// fast sigmoid-gelu: max abs err ~0.01 vs exact
__device__ __forceinline__ float gelu_fast(float x){
  return x / (1.0f + __expf(-1.702f * x));
}
// overflow-safe fast tanh
__device__ __forceinline__ float tanh_fast(float x){
  float e = __expf(2.0f * x);
  return 1.0f - 2.0f / (e + 1.0f);
}

// ---------------- K0: tiny tables (proven) ----------------
__global__ __launch_bounds__(256) void k_tables(
    const float* __restrict__ task, const float* __restrict__ eemb,
    const float* __restrict__ msg_W, const float* __restrict__ msg_b,
    const float* __restrict__ att_W1, const float* __restrict__ att_b1,
    const float* __restrict__ ma_W1, const float* __restrict__ ma_b1,
    const float* __restrict__ ma_W2, const float* __restrict__ ma_b2,
    const float* __restrict__ ua_W1, const float* __restrict__ ua_b1,
    const float* __restrict__ ua_W2, const float* __restrict__ ua_b2,
    float* __restrict__ tabs)
{
  __shared__ float s_in[512];
  __shared__ float s_h[512];
  int b = blockIdx.x, tid = threadIdx.x;
  if (b < 2){
    const float* W1 = b ? ua_W1 : ma_W1;  const float* b1 = b ? ua_b1 : ma_b1;
    const float* W2 = b ? ua_W2 : ma_W2;  const float* b2 = b ? ua_b2 : ma_b2;
    s_in[tid] = task[tid];
    __syncthreads();
    #pragma unroll
    for (int jj = 0; jj < 2; ++jj){
      int j = tid + jj*256;
      float acc = b1[j];
      for (int k = 0; k < 256; ++k) acc += s_in[k] * W1[k*512 + j];
      s_h[j] = gelu_f(acc);
    }
    __syncthreads();
    float o[2];
    #pragma unroll
    for (int jj = 0; jj < 2; ++jj){
      int j = tid + jj*256;
      float acc = b2[j];
      for (int k = 0; k < 512; ++k) acc += s_h[k] * W2[k*512 + j];
      o[jj] = acc;
    }
    float* scale = tabs + (b ? TAB_UPD_SCALE : TAB_MSG_SCALE);
    float* beta  = tabs + (b ? TAB_UPD_BETA  : TAB_MSG_BETA);
    scale[tid] = 1.0f + 0.5f * tanhf(o[0]);
    beta[tid]  = o[1];
  } else if (b == 2){
    s_in[tid] = task[tid];
    __syncthreads();
    float acc = att_b1[tid];
    for (int k = 0; k < 256; ++k) acc += s_in[k] * att_W1[(768 + k)*256 + tid];
    tabs[TAB_TASKC + tid] = acc;
  } else if (b < 19){
    int t = b - 3;
    s_in[tid] = eemb[t*256 + tid];
    __syncthreads();
    float acc = msg_b[tid];
    for (int k = 0; k < 256; ++k) acc += s_in[k] * msg_W[k*256 + tid];
    tabs[TAB_EM + t*256 + tid] = acc;
  } else {
    int t = b - 19;
    s_in[tid] = eemb[t*256 + tid];
    __syncthreads();
    float acc = 0.f;
    for (int k = 0; k < 256; ++k) acc += s_in[k] * att_W1[(512 + k)*256 + tid];
    tabs[TAB_EC + t*256 + tid] = acc;
  }
}

// ---------------- K0b: bf16 transposed weight copies (proven) ----------------
__global__ __launch_bounds__(256) void k_prep(
    const float* __restrict__ msg_W, const float* __restrict__ att_W1,
    const float* __restrict__ up_W1, const float* __restrict__ up_W2,
    unsigned short* __restrict__ WpreT, unsigned short* __restrict__ W1T,
    unsigned short* __restrict__ W2T)
{
  int b = blockIdx.x, tid = threadIdx.x;
  if (b < 768){
    int n = b;
    float v;
    if (n < 256)      v = msg_W[tid*256 + n];
    else if (n < 512) v = att_W1[tid*256 + (n - 256)];
    else              v = att_W1[(256 + tid)*256 + (n - 512)];
    WpreT[n*256 + tid] = f2bf(v);
  } else if (b < 1024){
    int n = b - 768;
    W1T[n*512 + tid]       = f2bf(up_W1[tid*256 + n]);
    W1T[n*512 + 256 + tid] = f2bf(up_W1[(256 + tid)*256 + n]);
  } else {
    int n = b - 1024;
    W2T[n*256 + tid] = f2bf(up_W2[tid*256 + n]);
  }
}

// ---------------- K1: G=[P1|M interleaved], P2b (proven) ----------------
__global__ __launch_bounds__(256) void k_gemm_pre(
    const float* __restrict__ X, const unsigned short* __restrict__ WpreT,
    const float* __restrict__ tabs,
    unsigned short* __restrict__ G, unsigned short* __restrict__ P2b)
{
  __shared__ __align__(16) unsigned short s_b[16*256]; // 8KB, swizzled elem ^= (n&7)<<3
  int tid = threadIdx.x, wv = tid >> 6, lane = tid & 63;
  int m0 = blockIdx.x*64 + wv*16;
  bool valid = (m0 < NN);
  int lo = lane & 15, hi = lane >> 4;
  bf16x8 a[8];
  if (valid){
    const float* xrow = X + (size_t)(m0 + lo)*256 + hi*8;
    #pragma unroll
    for (int kc = 0; kc < 8; ++kc){
      float4 f0 = *(const float4*)(xrow + kc*32);
      float4 f1 = *(const float4*)(xrow + kc*32 + 4);
      bf16x8 v;
      v[0]=(__bf16)f0.x; v[1]=(__bf16)f0.y; v[2]=(__bf16)f0.z; v[3]=(__bf16)f0.w;
      v[4]=(__bf16)f1.x; v[5]=(__bf16)f1.y; v[6]=(__bf16)f1.z; v[7]=(__bf16)f1.w;
      a[kc] = v;
    }
  }
  int sn = tid >> 4, sk0 = (tid & 15)*16;
  int sswz = (sn & 7) << 3;
  int rswz = (lo & 7) << 3;
  for (int nt = 0; nt < 48; ++nt){
    __syncthreads();
    {
      const unsigned short* gsrc = WpreT + (size_t)(nt*16 + sn)*256 + sk0;
      uint4 d0 = *(const uint4*)(gsrc);
      uint4 d1 = *(const uint4*)(gsrc + 8);
      *(uint4*)(s_b + sn*256 + (sk0 ^ sswz))       = d0;
      *(uint4*)(s_b + sn*256 + ((sk0 + 8) ^ sswz)) = d1;
    }
    __syncthreads();
    if (!valid) continue;
    f32x4 acc = {0.f, 0.f, 0.f, 0.f};
    #pragma unroll
    for (int kc = 0; kc < 8; ++kc){
      bf16x8 bfrag = *(const bf16x8*)(s_b + lo*256 + ((kc*32 + hi*8) ^ rswz));
      acc = __builtin_amdgcn_mfma_f32_16x16x32_bf16(a[kc], bfrag, acc, 0, 0, 0);
    }
    int n0 = nt*16;
    if (nt < 16){
      int j = n0 + lo;
      int elem = ((j >> 2) << 3) + 4 + (j & 3);
      unsigned short* grow = G + (size_t)(m0 + hi*4)*512 + elem;
      #pragma unroll
      for (int r = 0; r < 4; ++r) grow[(size_t)r*512] = f2bf(acc[r]);
    } else if (nt < 32){
      int j = n0 - 256 + lo;
      int elem = ((j >> 2) << 3) + (j & 3);
      unsigned short* grow = G + (size_t)(m0 + hi*4)*512 + elem;
      #pragma unroll
      for (int r = 0; r < 4; ++r) grow[(size_t)r*512] = f2bf(acc[r]);
    } else {
      int j = n0 - 512 + lo;
      float tcadd = tabs[TAB_TASKC + j];
      unsigned short* prow = P2b + (size_t)(m0 + hi*4)*256 + j;
      #pragma unroll
      for (int r = 0; r < 4; ++r) prow[(size_t)r*256] = f2bf(acc[r] + tcadd);
    }
  }
}

// ---------------- K2a: in-degree histogram ----------------
__global__ __launch_bounds__(256) void k_hist(
    const int* __restrict__ eidx, int* __restrict__ cnt)
{
  int e = blockIdx.x*256 + threadIdx.x;
  if (e < NE) atomicAdd(&cnt[eidx[NE + e]], 1);
}

// ---------------- K2b: exclusive prefix sum (1 block, 20 elems/thread) ----------------
__global__ __launch_bounds__(1024) void k_scan(
    const int* __restrict__ cnt, int* __restrict__ ptrs, int* __restrict__ pwork)
{
  __shared__ int s[1024];
  int tid = threadIdx.x;
  int loc[20];
  int tot = 0;
  #pragma unroll
  for (int j = 0; j < 20; ++j){
    int i = tid*20 + j;
    loc[j] = tot;
    tot += (i < NN) ? cnt[i] : 0;
  }
  s[tid] = tot;
  __syncthreads();
  #pragma unroll
  for (int off = 1; off < 1024; off <<= 1){
    int t = (tid >= off) ? s[tid - off] : 0;
    __syncthreads();
    s[tid] += t;
    __syncthreads();
  }
  int base = s[tid] - tot;
  #pragma unroll
  for (int j = 0; j < 20; ++j){
    int i = tid*20 + j;
    if (i < NN){
      ptrs[i]  = base + loc[j];
      pwork[i] = base + loc[j];
    }
  }
  if (tid == 1023) ptrs[NN] = s[1023];
}

// ---------------- K2c: CSR build ----------------
__global__ __launch_bounds__(256) void k_csr_build(
    const int* __restrict__ eidx, const int* __restrict__ etype,
    int* __restrict__ pwork, unsigned int* __restrict__ srcet)
{
  int e = blockIdx.x*256 + threadIdx.x;
  if (e < NE){
    int dst = eidx[NE + e];
    int pos = atomicAdd(&pwork[dst], 1);
    srcet[pos] = (unsigned int)eidx[e] | ((unsigned int)etype[e] << 16);
  }
}

// ---------------- K3: fused attention + aggregate (proven round-6) ----------------
__global__ __launch_bounds__(256) void k_agg(
    const int* __restrict__ ptrs, const unsigned int* __restrict__ srcet,
    const unsigned short* __restrict__ G, const unsigned short* __restrict__ P2b,
    const float* __restrict__ tabs, const float* __restrict__ attW2,
    const float* __restrict__ attb2, const float* __restrict__ escale,
    unsigned short* __restrict__ updB)
{
  int node = blockIdx.x*4 + (threadIdx.x >> 6);
  if (node >= NN) return;
  int lane = threadIdx.x & 63, c0 = lane*4;
  ushort4 p2 = *(const ushort4*)(P2b + (size_t)node*256 + c0);
  float q0 = bf2f(p2.x), q1 = bf2f(p2.y), q2 = bf2f(p2.z), q3 = bf2f(p2.w);
  float4 w2 = *(const float4*)(attW2 + c0);
  float sc = escale[0], bb = attb2[0];
  float4 ms = *(const float4*)(tabs + TAB_MSG_SCALE + c0);
  float4 mb = *(const float4*)(tabs + TAB_MSG_BETA  + c0);
  float4 us = *(const float4*)(tabs + TAB_UPD_SCALE + c0);
  float4 ub = *(const float4*)(tabs + TAB_UPD_BETA  + c0);
  int start = ptrs[node], end = ptrs[node + 1];
  float ax = 0.f, ay = 0.f, az = 0.f, aw = 0.f, W = 0.f;
  unsigned int se0 = 0, se1 = 0;
  u16x8 g0 = {0,0,0,0,0,0,0,0};
  if (start < end){
    se0 = srcet[start];
    g0 = *(const u16x8*)(G + (size_t)(se0 & 0xFFFFu)*512 + lane*8);
    if (start + 1 < end) se1 = srcet[start + 1];
  }
  for (int i = start; i < end; ++i){
    u16x8 g1 = g0;
    unsigned int se2 = 0;
    if (i + 1 < end) g1 = *(const u16x8*)(G + (size_t)(se1 & 0xFFFFu)*512 + lane*8);
    if (i + 2 < end) se2 = srcet[i + 2];
    int et = (int)(se0 >> 16);
    float4 ec = *(const float4*)(tabs + TAB_EC + et*256 + c0);
    float part = gelu_fast(bf2f(g0[0]) + q0 + ec.x)*w2.x
               + gelu_fast(bf2f(g0[1]) + q1 + ec.y)*w2.y
               + gelu_fast(bf2f(g0[2]) + q2 + ec.z)*w2.z
               + gelu_fast(bf2f(g0[3]) + q3 + ec.w)*w2.w;
    #pragma unroll
    for (int off = 32; off; off >>= 1) part += __shfl_xor(part, off);
    float w = 1.0f + sc*tanh_fast(part + bb);
    float4 em = *(const float4*)(tabs + TAB_EM + et*256 + c0);
    ax += w*(bf2f(g0[4]) + em.x);
    ay += w*(bf2f(g0[5]) + em.y);
    az += w*(bf2f(g0[6]) + em.z);
    aw += w*(bf2f(g0[7]) + em.w);
    W += w;
    se0 = se1; se1 = se2; g0 = g1;
  }
  float d = fmaxf(W, 1.0f), rd = 1.0f / d;
  ushort4 st = { f2bf((ms.x*ax + mb.x*W)*rd*us.x + ub.x),
                 f2bf((ms.y*ay + mb.y*W)*rd*us.y + ub.y),
                 f2bf((ms.z*az + mb.z*W)*rd*us.z + ub.z),
                 f2bf((ms.w*aw + mb.w*W)*rd*us.w + ub.w) };
  *(ushort4*)(updB + (size_t)node*256 + c0) = st;
}

// ---------------- K4 v3: 32-row dense MLP + residual + in-register LayerNorm ----------------
// 4 waves (n-slices), 2 m-tiles share every B-fragment. No s_y: LN from registers.
__device__ __forceinline__ bf16x8 ldA(const float* xrow, const unsigned short* urow, int ke){
  if (ke < 256){
    float4 f0 = *(const float4*)(xrow + ke);
    float4 f1 = *(const float4*)(xrow + ke + 4);
    bf16x8 v;
    v[0]=(__bf16)f0.x; v[1]=(__bf16)f0.y; v[2]=(__bf16)f0.z; v[3]=(__bf16)f0.w;
    v[4]=(__bf16)f1.x; v[5]=(__bf16)f1.y; v[6]=(__bf16)f1.z; v[7]=(__bf16)f1.w;
    return v;
  }
  return *(const bf16x8*)(urow + (ke - 256));
}

__global__ __launch_bounds__(256) void k_mlp(
    const float* __restrict__ X, const unsigned short* __restrict__ updB,
    const unsigned short* __restrict__ W1T, const unsigned short* __restrict__ W2T,
    const float* __restrict__ up_b1, const float* __restrict__ up_b2,
    const float* __restrict__ ln_g, const float* __restrict__ ln_b,
    float* __restrict__ out)
{
  __shared__ __align__(16) unsigned short s_H[32*256]; // bf16, ^=(row&7)<<3
  __shared__ float s_sum[4*32], s_sq[4*32];
  __shared__ float s_mu[32], s_rs[32];
  int m0 = blockIdx.x*32;
  int tid = threadIdx.x;
  int wv = tid >> 6, lane = tid & 63, lo = lane & 15, hi = lane >> 4;

  const float* x0 = X + (size_t)(m0 + lo)*256;
  const float* x1 = x0 + 16*256;
  const unsigned short* u0 = updB + (size_t)(m0 + lo)*256;
  const unsigned short* u1 = u0 + 16*256;

  // GEMM1: H = gelu([X|upd] @ up_W1 + b1); wave wv covers cols [wv*64, wv*64+64)
  f32x4 acc0[4], acc1[4];
  #pragma unroll
  for (int t = 0; t < 4; ++t){
    float b = up_b1[wv*64 + t*16 + lo];
    acc0[t] = (f32x4){b, b, b, b};
    acc1[t] = acc0[t];
  }
  #pragma unroll
  for (int kc = 0; kc < 16; ++kc){
    int ke = kc*32 + hi*8;
    bf16x8 a0 = ldA(x0, u0, ke);
    bf16x8 a1 = ldA(x1, u1, ke);
    #pragma unroll
    for (int t = 0; t < 4; ++t){
      int n = wv*64 + t*16 + lo;
      bf16x8 bf = *(const bf16x8*)(W1T + (size_t)n*512 + ke);
      acc0[t] = __builtin_amdgcn_mfma_f32_16x16x32_bf16(a0, bf, acc0[t], 0, 0, 0);
      acc1[t] = __builtin_amdgcn_mfma_f32_16x16x32_bf16(a1, bf, acc1[t], 0, 0, 0);
    }
  }
  #pragma unroll
  for (int t = 0; t < 4; ++t){
    #pragma unroll
    for (int r = 0; r < 4; ++r){
      int row0 = hi*4 + r, n = wv*64 + t*16 + lo;
      s_H[(row0 << 8) | (n ^ ((row0 & 7) << 3))] = f2bf(gelu_fast(acc0[t][r]));
      int row1 = row0 + 16;
      s_H[(row1 << 8) | (n ^ ((row1 & 7) << 3))] = f2bf(gelu_fast(acc1[t][r]));
    }
  }
  __syncthreads();

  // GEMM2: updated = H @ up_W2 + b2 (both m-tiles share B)
  f32x4 y0[4], y1[4];
  #pragma unroll
  for (int t = 0; t < 4; ++t){
    float b = up_b2[wv*64 + t*16 + lo];
    y0[t] = (f32x4){b, b, b, b};
    y1[t] = y0[t];
  }
  #pragma unroll
  for (int kc = 0; kc < 8; ++kc){
    int ke = kc*32 + hi*8;
    bf16x8 af0 = *(const bf16x8*)(s_H + ((lo << 8) | (ke ^ ((lo & 7) << 3))));
    int r1 = lo + 16;
    bf16x8 af1 = *(const bf16x8*)(s_H + ((r1 << 8) | (ke ^ ((r1 & 7) << 3))));
    #pragma unroll
    for (int t = 0; t < 4; ++t){
      int n = wv*64 + t*16 + lo;
      bf16x8 bf = *(const bf16x8*)(W2T + (size_t)n*256 + ke);
      y0[t] = __builtin_amdgcn_mfma_f32_16x16x32_bf16(af0, bf, y0[t], 0, 0, 0);
      y1[t] = __builtin_amdgcn_mfma_f32_16x16x32_bf16(af1, bf, y1[t], 0, 0, 0);
    }
  }

  // residual: y += X (in registers)
  #pragma unroll
  for (int t = 0; t < 4; ++t){
    #pragma unroll
    for (int r = 0; r < 4; ++r){
      int row0 = hi*4 + r, n = wv*64 + t*16 + lo;
      y0[t][r] += X[(size_t)(m0 + row0)*256 + n];
      y1[t][r] += X[(size_t)(m0 + row0 + 16)*256 + n];
    }
  }

  // in-register LN partials: per (m, r) sum/sq over t, then over 16-lane group
  float ps[2][4], pq[2][4];
  #pragma unroll
  for (int r = 0; r < 4; ++r){
    float s0 = 0.f, q0 = 0.f, s1 = 0.f, q1 = 0.f;
    #pragma unroll
    for (int t = 0; t < 4; ++t){
      s0 += y0[t][r]; q0 += y0[t][r]*y0[t][r];
      s1 += y1[t][r]; q1 += y1[t][r]*y1[t][r];
    }
    #pragma unroll
    for (int off = 1; off < 16; off <<= 1){
      s0 += __shfl_xor(s0, off); q0 += __shfl_xor(q0, off);
      s1 += __shfl_xor(s1, off); q1 += __shfl_xor(q1, off);
    }
    ps[0][r] = s0; pq[0][r] = q0;
    ps[1][r] = s1; pq[1][r] = q1;
  }
  if (lo == 0){
    #pragma unroll
    for (int m = 0; m < 2; ++m){
      #pragma unroll
      for (int r = 0; r < 4; ++r){
        int row = m*16 + hi*4 + r;
        s_sum[wv*32 + row] = ps[m][r];
        s_sq [wv*32 + row] = pq[m][r];
      }
    }
  }
  __syncthreads();
  if (tid < 32){
    float sum = s_sum[tid] + s_sum[32 + tid] + s_sum[64 + tid] + s_sum[96 + tid];
    float sq  = s_sq[tid]  + s_sq[32 + tid]  + s_sq[64 + tid]  + s_sq[96 + tid];
    float mu = sum * (1.0f/256.0f);
    float var = sq * (1.0f/256.0f) - mu*mu;
    s_mu[tid] = mu;
    s_rs[tid] = rsqrtf(var + 1e-5f);
  }
  __syncthreads();

  // normalize + store
  #pragma unroll
  for (int t = 0; t < 4; ++t){
    int n = wv*64 + t*16 + lo;
    float lg = ln_g[n], lb = ln_b[n];
    #pragma unroll
    for (int r = 0; r < 4; ++r){
      int row0 = hi*4 + r, row1 = row0 + 16;
      out[(size_t)(m0 + row0)*256 + n] = (y0[t][r] - s_mu[row0]) * s_rs[row0] * lg + lb;
      out[(size_t)(m0 + row1)*256 + n] = (y1[t][r] - s_mu[row1]) * s_rs[row1] * lg + lb;
    }
  }
}

extern "C" void kernel_launch(void* const* d_in, const int* in_sizes, int n_in,
                              void* d_out, int out_size, void* d_ws, size_t ws_size,
                              hipStream_t stream)
{
  (void)in_sizes; (void)n_in; (void)out_size;
  if (ws_size < WS_NEED) return;
  const float* X      = (const float*)d_in[0];
  const int*   eidx   = (const int*)d_in[1];
  const int*   etype  = (const int*)d_in[2];
  const float* task   = (const float*)d_in[3];
  const float* eemb   = (const float*)d_in[4];
  const float* msg_W  = (const float*)d_in[5];
  const float* msg_b  = (const float*)d_in[6];
  const float* att_W1 = (const float*)d_in[7];
  const float* att_b1 = (const float*)d_in[8];
  const float* att_W2 = (const float*)d_in[9];
  const float* att_b2 = (const float*)d_in[10];
  const float* escale = (const float*)d_in[11];
  const float* ma_W1  = (const float*)d_in[12];
  const float* ma_b1  = (const float*)d_in[13];
  const float* ma_W2  = (const float*)d_in[14];
  const float* ma_b2  = (const float*)d_in[15];
  const float* up_W1  = (const float*)d_in[16];
  const float* up_b1  = (const float*)d_in[17];
  const float* up_W2  = (const float*)d_in[18];
  const float* up_b2  = (const float*)d_in[19];
  const float* ua_W1  = (const float*)d_in[20];
  const float* ua_b1  = (const float*)d_in[21];
  const float* ua_W2  = (const float*)d_in[22];
  const float* ua_b2  = (const float*)d_in[23];
  const float* ln_g   = (const float*)d_in[24];
  const float* ln_b   = (const float*)d_in[25];
  char* ws = (char*)d_ws;
  float* tabs = (float*)ws;
  unsigned short* WpreT = (unsigned short*)(ws + OFF_WPRET);
  unsigned short* W1T   = (unsigned short*)(ws + OFF_W1T);
  unsigned short* W2T   = (unsigned short*)(ws + OFF_W2T);
  int*          cnt   = (int*)(ws + OFF_CNT);
  int*          ptrs  = (int*)(ws + OFF_PTRS);
  int*          pwork = (int*)(ws + OFF_PWORK);
  unsigned int* srcet = (unsigned int*)(ws + OFF_SRCET);
  unsigned short* updB = (unsigned short*)(ws + OFF_UPDB);
  unsigned short* G    = (unsigned short*)(ws + OFF_G);
  unsigned short* P2b  = (unsigned short*)(ws + OFF_P2B);
  float* out = (float*)d_out;

  hipMemsetAsync(cnt, 0, (size_t)NN*4, stream);
  k_tables<<<35, 256, 0, stream>>>(task, eemb, msg_W, msg_b, att_W1, att_b1,
                                   ma_W1, ma_b1, ma_W2, ma_b2,
                                   ua_W1, ua_b1, ua_W2, ua_b2, tabs);
  k_prep<<<1280, 256, 0, stream>>>(msg_W, att_W1, up_W1, up_W2, WpreT, W1T, W2T);
  k_gemm_pre<<<(NN + 63)/64, 256, 0, stream>>>(X, WpreT, tabs, G, P2b);
  k_hist<<<(NE + 255)/256, 256, 0, stream>>>(eidx, cnt);
  k_scan<<<1, 1024, 0, stream>>>(cnt, ptrs, pwork);
  k_csr_build<<<(NE + 255)/256, 256, 0, stream>>>(eidx, etype, pwork, srcet);
  k_agg<<<(NN + 3)/4, 256, 0, stream>>>(ptrs, srcet, G, P2b, tabs,
                                        att_W2, att_b2, escale, updB);
  k_mlp<<<NN/32, 256, 0, stream>>>(X, updB, W1T, W2T, up_b1, up_b2,
                                   ln_g, ln_b, out);
}